// Round 1
// baseline (578.178 us; speedup 1.0000x reference)
//
#include <hip/hip_runtime.h>
#include <stdint.h>

// Problem constants: B=1, S=2048, D=4096, H=32, KV=8, HD=128, NREP=4
#define S_LEN 2048
#define D_DIM 4096
#define N_HEADS 32
#define KV_HEADS 8
#define HEAD_DIM 128
#define SCALE_F 0.08838834764831845f

typedef __bf16 bf16x8_t __attribute__((ext_vector_type(8)));
typedef unsigned short u16x8 __attribute__((ext_vector_type(8)));
typedef float f32x4 __attribute__((ext_vector_type(4)));

__device__ __forceinline__ unsigned short f2bf(float f) {
  unsigned int u = __float_as_uint(f);
  unsigned int r = ((u >> 16) & 1u) + 0x7FFFu;  // RNE
  return (unsigned short)((u + r) >> 16);
}
__device__ __forceinline__ float bf2f(unsigned short s) {
  return __uint_as_float(((unsigned int)s) << 16);
}
__device__ __forceinline__ f32x4 mfma16(u16x8 a, u16x8 b, f32x4 c) {
  return __builtin_amdgcn_mfma_f32_16x16x32_bf16(
      __builtin_bit_cast(bf16x8_t, a), __builtin_bit_cast(bf16x8_t, b), c, 0, 0, 0);
}
__device__ __forceinline__ void gload_lds16(const void* g, void* l) {
  __builtin_amdgcn_global_load_lds((const __attribute__((address_space(1))) void*)g,
                                   (__attribute__((address_space(3))) void*)l, 16, 0, 0);
}

// ---------------- f32 -> bf16 convert ----------------
__global__ void cvtk(const float* __restrict__ in, unsigned short* __restrict__ out, int n) {
  int i = (blockIdx.x * blockDim.x + threadIdx.x) * 4;
  if (i >= n) return;
  float4 v = *(const float4*)(in + i);
  unsigned int p0 = (unsigned int)f2bf(v.x) | ((unsigned int)f2bf(v.y) << 16);
  unsigned int p1 = (unsigned int)f2bf(v.z) | ((unsigned int)f2bf(v.w) << 16);
  *(uint2*)(out + i) = make_uint2(p0, p1);
}

// ---------------- RoPE (optionally folds SCALE into Q) ----------------
__global__ void ropek(unsigned short* __restrict__ buf, const float* __restrict__ fc,
                      int hshift, int rowstride, float scale) {
  int idx = blockIdx.x * blockDim.x + threadIdx.x;  // over S * nH * 64
  int j = idx & 63;
  int h = (idx >> 6) & ((1 << hshift) - 1);
  int s = idx >> (6 + hshift);
  unsigned short* p = buf + (size_t)s * rowstride + h * 128 + 2 * j;
  float cs = fc[(s * 64 + j) * 2];
  float sn = fc[(s * 64 + j) * 2 + 1];
  float a = bf2f(p[0]), b = bf2f(p[1]);
  unsigned int o0 = f2bf((a * cs - b * sn) * scale);
  unsigned int o1 = f2bf((a * sn + b * cs) * scale);
  *(unsigned int*)p = o0 | (o1 << 16);
}

// ---------------- V transpose: KVb[s][1024+e] -> Vt[e][s] ----------------
__global__ void transpV(const unsigned short* __restrict__ in, unsigned short* __restrict__ out) {
  __shared__ unsigned short tile[32][33];
  int e0 = blockIdx.x * 32, s0 = blockIdx.y * 32;
  int tx = threadIdx.x, ty = threadIdx.y;  // 32 x 8
#pragma unroll
  for (int j = 0; j < 4; ++j)
    tile[ty + j * 8][tx] = in[(size_t)(s0 + ty + j * 8) * 2048 + 1024 + e0 + tx];
  __syncthreads();
#pragma unroll
  for (int j = 0; j < 4; ++j)
    out[(size_t)(e0 + ty + j * 8) * 2048 + s0 + tx] = tile[tx][ty + j * 8];
}

// ---------------- bf16 GEMM: C[M][N] = A[M][K] * BT[N][K]^T  (m97 structure) ----------------
template <int OUTBF16>
__global__ __launch_bounds__(256) void gemm_bt(const unsigned short* __restrict__ A,
                                               const unsigned short* __restrict__ BT,
                                               void* __restrict__ Cout, int M, int N, int K) {
  __shared__ __align__(16) unsigned short Atile[128 * 32];
  __shared__ __align__(16) unsigned short Btile[128 * 32];
  const int tid = threadIdx.x;
  const int w = tid >> 6, l = tid & 63;
  const int c = l & 15, h = l >> 4;
  const int m0 = blockIdx.y * 128, n0 = blockIdx.x * 128;
  const int wr = (w >> 1) * 64, wc = (w & 1) * 64;
  f32x4 acc[4][4];
#pragma unroll
  for (int mf = 0; mf < 4; ++mf)
#pragma unroll
    for (int nf = 0; nf < 4; ++nf)
#pragma unroll
      for (int r = 0; r < 4; ++r) acc[mf][nf][r] = 0.f;

  const int nk = K >> 5;
  for (int kt = 0; kt < nk; ++kt) {
    __syncthreads();
    const int kb = kt * 32;
#pragma unroll
    for (int i = 0; i < 4; ++i) {
      int chunk = w * 4 + i;              // 0..7 -> A, 8..15 -> B
      int eoff = (chunk & 7) * 512 + l * 8;
      int row = eoff >> 5, col = eoff & 31;
      const unsigned short* gsrc = (chunk & 8)
          ? (BT + (size_t)(n0 + row) * K + kb + col)
          : (A + (size_t)(m0 + row) * K + kb + col);
      unsigned short* ldst = ((chunk & 8) ? Btile : Atile) + eoff;
      gload_lds16(gsrc, ldst);
    }
    __syncthreads();
    u16x8 af[4], bfr[4];
#pragma unroll
    for (int mf = 0; mf < 4; ++mf)
      af[mf] = *(const u16x8*)&Atile[(wr + mf * 16 + c) * 32 + h * 8];
#pragma unroll
    for (int nf = 0; nf < 4; ++nf)
      bfr[nf] = *(const u16x8*)&Btile[(wc + nf * 16 + c) * 32 + h * 8];
#pragma unroll
    for (int mf = 0; mf < 4; ++mf)
#pragma unroll
      for (int nf = 0; nf < 4; ++nf)
        acc[mf][nf] = mfma16(af[mf], bfr[nf], acc[mf][nf]);
  }
  // epilogue: C/D layout col=lane&15, row=(lane>>4)*4+r  [m89-verified]
#pragma unroll
  for (int mf = 0; mf < 4; ++mf)
#pragma unroll
    for (int nf = 0; nf < 4; ++nf)
#pragma unroll
      for (int r = 0; r < 4; ++r) {
        int row = m0 + wr + mf * 16 + h * 4 + r;
        int col = n0 + wc + nf * 16 + c;
        float v = acc[mf][nf][r];
        if (OUTBF16)
          ((unsigned short*)Cout)[(size_t)row * N + col] = f2bf(v);
        else
          ((float*)Cout)[(size_t)row * N + col] = v;
      }
}

// ---------------- flash attention (causal GQA) ----------------
// grid: (32 q-tiles of 64 rows, 32 heads); 4 waves, each owns 16 q-rows.
__global__ __launch_bounds__(256) void attnk(const unsigned short* __restrict__ Q,
                                             const unsigned short* __restrict__ KV,
                                             const unsigned short* __restrict__ Vt,
                                             unsigned short* __restrict__ Ao) {
  __shared__ __align__(16) unsigned short Kt[32 * 128];   // K tile, XOR-swizzled rows (256B)
  __shared__ __align__(16) unsigned short Vtt[128 * 32];  // V^T tile [hd][key]
  __shared__ __align__(16) unsigned short Pl[4][16 * 40]; // per-wave P, pitch 40 (80B, 16B-mult)
  const int tid = threadIdx.x;
  const int w = tid >> 6, l = tid & 63, c = l & 15, h = l >> 4;
  const int qt = blockIdx.x, head = blockIdx.y;
  const int g = head >> 2;  // kv group
  const int qb = qt * 64 + w * 16;

  // Q fragments in registers (A-frag: row = lane&15, k = h*8+j per 32-chunk). Q pre-scaled.
  u16x8 qf[4];
#pragma unroll
  for (int kc = 0; kc < 4; ++kc)
    qf[kc] = *(const u16x8*)&Q[(size_t)(qb + c) * 4096 + head * 128 + kc * 32 + h * 8];

  f32x4 accO[8];
#pragma unroll
  for (int nf = 0; nf < 8; ++nf)
#pragma unroll
    for (int r = 0; r < 4; ++r) accO[nf][r] = 0.f;
  float m_run[4], l_run[4];
#pragma unroll
  for (int r = 0; r < 4; ++r) { m_run[r] = -3.0e38f; l_run[r] = 0.f; }

  const int nkv = 2 * qt + 2;
  for (int kvt = 0; kvt < nkv; ++kvt) {
    __syncthreads();
    // stage K (pre-swizzled source so swizzled reads are conflict-light) and V^T
#pragma unroll
    for (int i = 0; i < 2; ++i) {
      int B = (w * 2 + i) * 1024 + l * 16;  // byte in 8KB tile
      int row = B >> 8;                      // key row (256B rows)
      int slot = (B >> 4) & 15;
      int srcb = (slot ^ (row & 7)) << 4;
      const unsigned short* gk = KV + (size_t)(kvt * 32 + row) * 2048 + g * 128 + (srcb >> 1);
      gload_lds16(gk, Kt + (B >> 1));
      int hd = B >> 6;                       // V^T: 64B rows
      int ko = (B & 63) >> 1;
      const unsigned short* gv = Vt + (size_t)(g * 128 + hd) * 2048 + kvt * 32 + ko;
      gload_lds16(gv, Vtt + (B >> 1));
    }
    __syncthreads();

    // S = Q K^T (C: row=q=h*4+r, col=key=c+16*nf)
    f32x4 sacc[2];
#pragma unroll
    for (int nf = 0; nf < 2; ++nf) {
#pragma unroll
      for (int r = 0; r < 4; ++r) sacc[nf][r] = 0.f;
#pragma unroll
      for (int kc = 0; kc < 4; ++kc) {
        int row = nf * 16 + c;
        int byteo = (kc * 64 + h * 16) ^ ((row & 7) << 4);
        u16x8 kf = *(const u16x8*)&Kt[row * 128 + (byteo >> 1)];
        sacc[nf] = mfma16(qf[kc], kf, sacc[nf]);
      }
    }

    // online softmax
    float p0[4], p1[4], al[4];
    {
      int key0 = kvt * 32 + c, key1 = key0 + 16;
      float mt[4];
#pragma unroll
      for (int r = 0; r < 4; ++r) {
        int qrow = qb + h * 4 + r;
        float s0 = (key0 <= qrow) ? sacc[0][r] : -1e9f;
        float s1 = (key1 <= qrow) ? sacc[1][r] : -1e9f;
        p0[r] = s0; p1[r] = s1;
        mt[r] = fmaxf(s0, s1);
      }
#pragma unroll
      for (int d = 1; d < 16; d <<= 1)
#pragma unroll
        for (int r = 0; r < 4; ++r) mt[r] = fmaxf(mt[r], __shfl_xor(mt[r], d, 64));
#pragma unroll
      for (int r = 0; r < 4; ++r) {
        float mn = fmaxf(m_run[r], mt[r]);
        al[r] = __expf(m_run[r] - mn);
        p0[r] = __expf(p0[r] - mn);
        p1[r] = __expf(p1[r] - mn);
        l_run[r] = l_run[r] * al[r] + p0[r] + p1[r];
        m_run[r] = mn;
      }
    }
#pragma unroll
    for (int nf = 0; nf < 8; ++nf)
#pragma unroll
      for (int r = 0; r < 4; ++r) accO[nf][r] *= al[r];

    // P: C-layout -> LDS -> A-frag layout (within-wave region)
#pragma unroll
    for (int r = 0; r < 4; ++r) {
      Pl[w][(h * 4 + r) * 40 + c] = f2bf(p0[r]);
      Pl[w][(h * 4 + r) * 40 + 16 + c] = f2bf(p1[r]);
    }
    asm volatile("s_waitcnt lgkmcnt(0)" ::: "memory");
    __builtin_amdgcn_sched_barrier(0);
    u16x8 pa = *(const u16x8*)&Pl[w][c * 40 + h * 8];
#pragma unroll
    for (int nf = 0; nf < 8; ++nf) {
      u16x8 vf = *(const u16x8*)&Vtt[(nf * 16 + c) * 32 + h * 8];
      accO[nf] = mfma16(pa, vf, accO[nf]);
    }
  }

  // finalize: reduce l across the 16 key-lanes, divide, store bf16
  float linv[4];
#pragma unroll
  for (int r = 0; r < 4; ++r) {
    float s = l_run[r];
#pragma unroll
    for (int d = 1; d < 16; d <<= 1) s += __shfl_xor(s, d, 64);
    linv[r] = 1.0f / s;
  }
#pragma unroll
  for (int nf = 0; nf < 8; ++nf)
#pragma unroll
    for (int r = 0; r < 4; ++r) {
      int row = qb + h * 4 + r;
      int col = head * 128 + nf * 16 + c;
      Ao[(size_t)row * 4096 + col] = f2bf(accO[nf][r] * linv[r]);
    }
}

extern "C" void kernel_launch(void* const* d_in, const int* in_sizes, int n_in,
                              void* d_out, int out_size, void* d_ws, size_t ws_size,
                              hipStream_t stream) {
  (void)in_sizes; (void)n_in; (void)out_size; (void)ws_size;
  const float* x  = (const float*)d_in[0];
  const float* fc = (const float*)d_in[1];
  // d_in[2] = mask: exactly triu(-1e9, k=1) -> causal handled in-kernel
  const float* wq = (const float*)d_in[3];
  const float* wk = (const float*)d_in[4];
  const float* wv = (const float*)d_in[5];
  const float* wo = (const float*)d_in[6];

  // workspace layout (bf16 elements); total 73,400,320 elems = ~140 MB
  unsigned short* xb   = (unsigned short*)d_ws;
  unsigned short* wqb  = xb   + (size_t)8  * 1024 * 1024;
  unsigned short* wkvb = wqb  + (size_t)16 * 1024 * 1024;  // wk rows then wv rows
  unsigned short* wob  = wkvb + (size_t)8  * 1024 * 1024;
  unsigned short* Qb   = wob  + (size_t)16 * 1024 * 1024;
  unsigned short* KVb  = Qb   + (size_t)8  * 1024 * 1024;  // [s][0..1023]=K, [1024..2047]=V
  unsigned short* Vtb  = KVb  + (size_t)4  * 1024 * 1024;  // V^T [e][s]
  unsigned short* Ab   = Vtb  + (size_t)2  * 1024 * 1024;

  cvtk<<<dim3(8 * 1024 * 1024 / 1024), 256, 0, stream>>>(x, xb, 8 * 1024 * 1024);
  cvtk<<<dim3(16 * 1024 * 1024 / 1024), 256, 0, stream>>>(wq, wqb, 16 * 1024 * 1024);
  cvtk<<<dim3(4 * 1024 * 1024 / 1024), 256, 0, stream>>>(wk, wkvb, 4 * 1024 * 1024);
  cvtk<<<dim3(4 * 1024 * 1024 / 1024), 256, 0, stream>>>(wv, wkvb + (size_t)4 * 1024 * 1024,
                                                         4 * 1024 * 1024);
  cvtk<<<dim3(16 * 1024 * 1024 / 1024), 256, 0, stream>>>(wo, wob, 16 * 1024 * 1024);

  gemm_bt<1><<<dim3(4096 / 128, 2048 / 128), 256, 0, stream>>>(xb, wqb, Qb, 2048, 4096, 4096);
  gemm_bt<1><<<dim3(2048 / 128, 2048 / 128), 256, 0, stream>>>(xb, wkvb, KVb, 2048, 2048, 4096);

  ropek<<<dim3(2048 * 32 * 64 / 256), 256, 0, stream>>>(Qb, fc, 5, 4096, SCALE_F);
  ropek<<<dim3(2048 * 8 * 64 / 256), 256, 0, stream>>>(KVb, fc, 3, 2048, 1.0f);
  transpV<<<dim3(32, 64), dim3(32, 8), 0, stream>>>(KVb, Vtb);

  attnk<<<dim3(32, 32), 256, 0, stream>>>(Qb, KVb, Vtb, Ab);

  gemm_bt<0><<<dim3(4096 / 128, 2048 / 128), 256, 0, stream>>>(Ab, wob, d_out, 2048, 4096, 4096);
}

// Round 2
// 535.212 us; speedup vs baseline: 1.0803x; 1.0803x over previous
//
#include <hip/hip_runtime.h>
#include <stdint.h>

// Problem constants: B=1, S=2048, D=4096, H=32, KV=8, HD=128, NREP=4
#define SCALE_F 0.08838834764831845f

typedef __bf16 bf16x8_t __attribute__((ext_vector_type(8)));
typedef unsigned short u16x8 __attribute__((ext_vector_type(8)));
typedef float f32x4 __attribute__((ext_vector_type(4)));
typedef float f32x16 __attribute__((ext_vector_type(16)));

__device__ __forceinline__ unsigned short f2bf(float f) {
  unsigned int u = __float_as_uint(f);
  unsigned int r = ((u >> 16) & 1u) + 0x7FFFu;  // RNE
  return (unsigned short)((u + r) >> 16);
}
__device__ __forceinline__ float bf2f(unsigned short s) {
  return __uint_as_float(((unsigned int)s) << 16);
}
__device__ __forceinline__ f32x4 mfma16(u16x8 a, u16x8 b, f32x4 c) {
  return __builtin_amdgcn_mfma_f32_16x16x32_bf16(
      __builtin_bit_cast(bf16x8_t, a), __builtin_bit_cast(bf16x8_t, b), c, 0, 0, 0);
}
__device__ __forceinline__ f32x16 mfma32(u16x8 a, u16x8 b, f32x16 c) {
  return __builtin_amdgcn_mfma_f32_32x32x16_bf16(
      __builtin_bit_cast(bf16x8_t, a), __builtin_bit_cast(bf16x8_t, b), c, 0, 0, 0);
}
__device__ __forceinline__ unsigned int cvtpk(float lo, float hi) {
  unsigned int r;
  asm("v_cvt_pk_bf16_f32 %0, %1, %2" : "=v"(r) : "v"(lo), "v"(hi));
  return r;
}
__device__ __forceinline__ void gload_lds16(const void* g, void* l) {
  __builtin_amdgcn_global_load_lds((const __attribute__((address_space(1))) void*)g,
                                   (__attribute__((address_space(3))) void*)l, 16, 0, 0);
}

// ---------------- f32 -> bf16 convert ----------------
__global__ void cvtk(const float* __restrict__ in, unsigned short* __restrict__ out, int n) {
  int i = (blockIdx.x * blockDim.x + threadIdx.x) * 4;
  if (i >= n) return;
  float4 v = *(const float4*)(in + i);
  unsigned int p0 = (unsigned int)f2bf(v.x) | ((unsigned int)f2bf(v.y) << 16);
  unsigned int p1 = (unsigned int)f2bf(v.z) | ((unsigned int)f2bf(v.w) << 16);
  *(uint2*)(out + i) = make_uint2(p0, p1);
}

// ---------------- RoPE (optionally folds SCALE into Q) ----------------
__global__ void ropek(unsigned short* __restrict__ buf, const float* __restrict__ fc,
                      int hshift, int rowstride, float scale) {
  int idx = blockIdx.x * blockDim.x + threadIdx.x;  // over S * nH * 64
  int j = idx & 63;
  int h = (idx >> 6) & ((1 << hshift) - 1);
  int s = idx >> (6 + hshift);
  unsigned short* p = buf + (size_t)s * rowstride + h * 128 + 2 * j;
  float cs = fc[(s * 64 + j) * 2];
  float sn = fc[(s * 64 + j) * 2 + 1];
  float a = bf2f(p[0]), b = bf2f(p[1]);
  unsigned int o0 = f2bf((a * cs - b * sn) * scale);
  unsigned int o1 = f2bf((a * sn + b * cs) * scale);
  *(unsigned int*)p = o0 | (o1 << 16);
}

// ---------------- V transpose: KVb[s][1024+e] -> Vt[e][s] ----------------
__global__ void transpV(const unsigned short* __restrict__ in, unsigned short* __restrict__ out) {
  __shared__ unsigned short tile[32][33];
  int e0 = blockIdx.x * 32, s0 = blockIdx.y * 32;
  int tx = threadIdx.x, ty = threadIdx.y;  // 32 x 8
#pragma unroll
  for (int j = 0; j < 4; ++j)
    tile[ty + j * 8][tx] = in[(size_t)(s0 + ty + j * 8) * 2048 + 1024 + e0 + tx];
  __syncthreads();
#pragma unroll
  for (int j = 0; j < 4; ++j)
    out[(size_t)(e0 + ty + j * 8) * 2048 + s0 + tx] = tile[tx][ty + j * 8];
}

// ---------------- bf16 GEMM: C[M][N] = A[M][K] * BT[N][K]^T  (m97 structure) ----------------
template <int OUTBF16>
__global__ __launch_bounds__(256) void gemm_bt(const unsigned short* __restrict__ A,
                                               const unsigned short* __restrict__ BT,
                                               void* __restrict__ Cout, int M, int N, int K) {
  __shared__ __align__(16) unsigned short Atile[128 * 32];
  __shared__ __align__(16) unsigned short Btile[128 * 32];
  const int tid = threadIdx.x;
  const int w = tid >> 6, l = tid & 63;
  const int c = l & 15, h = l >> 4;
  const int m0 = blockIdx.y * 128, n0 = blockIdx.x * 128;
  const int wr = (w >> 1) * 64, wc = (w & 1) * 64;
  f32x4 acc[4][4];
#pragma unroll
  for (int mf = 0; mf < 4; ++mf)
#pragma unroll
    for (int nf = 0; nf < 4; ++nf)
#pragma unroll
      for (int r = 0; r < 4; ++r) acc[mf][nf][r] = 0.f;

  const int nk = K >> 5;
  for (int kt = 0; kt < nk; ++kt) {
    __syncthreads();
    const int kb = kt * 32;
#pragma unroll
    for (int i = 0; i < 4; ++i) {
      int chunk = w * 4 + i;              // 0..7 -> A, 8..15 -> B
      int eoff = (chunk & 7) * 512 + l * 8;
      int row = eoff >> 5, col = eoff & 31;
      const unsigned short* gsrc = (chunk & 8)
          ? (BT + (size_t)(n0 + row) * K + kb + col)
          : (A + (size_t)(m0 + row) * K + kb + col);
      unsigned short* ldst = ((chunk & 8) ? Btile : Atile) + eoff;
      gload_lds16(gsrc, ldst);
    }
    __syncthreads();
    u16x8 af[4], bfr[4];
#pragma unroll
    for (int mf = 0; mf < 4; ++mf)
      af[mf] = *(const u16x8*)&Atile[(wr + mf * 16 + c) * 32 + h * 8];
#pragma unroll
    for (int nf = 0; nf < 4; ++nf)
      bfr[nf] = *(const u16x8*)&Btile[(wc + nf * 16 + c) * 32 + h * 8];
#pragma unroll
    for (int mf = 0; mf < 4; ++mf)
#pragma unroll
      for (int nf = 0; nf < 4; ++nf)
        acc[mf][nf] = mfma16(af[mf], bfr[nf], acc[mf][nf]);
  }
  // epilogue: C/D layout col=lane&15, row=(lane>>4)*4+r  [m89-verified]
#pragma unroll
  for (int mf = 0; mf < 4; ++mf)
#pragma unroll
    for (int nf = 0; nf < 4; ++nf)
#pragma unroll
      for (int r = 0; r < 4; ++r) {
        int row = m0 + wr + mf * 16 + h * 4 + r;
        int col = n0 + wc + nf * 16 + c;
        float v = acc[mf][nf][r];
        if (OUTBF16)
          ((unsigned short*)Cout)[(size_t)row * N + col] = f2bf(v);
        else
          ((float*)Cout)[(size_t)row * N + col] = v;
      }
}

// ---------------- LDS-free flash attention (causal GQA), 32x32x16 MFMA ----------------
// One wave per 32 q-rows. S = mfma(K,Q): lane owns q-col = lane&31 -> in-lane softmax.
// K / V^T fragments loaded directly from global (L2-resident: 1MB per kv-group, kvg = b%8
// keeps one group per XCD). Blocks ordered by descending q-group for dispatch backfill.
__global__ __launch_bounds__(64) void attnk(const unsigned short* __restrict__ Q,
                                            const unsigned short* __restrict__ KV,
                                            const unsigned short* __restrict__ Vt,
                                            unsigned short* __restrict__ Ao) {
  const int l = threadIdx.x;
  const int q31 = l & 31, hi = l >> 5;
  const int b = blockIdx.x;
  const int kvg = b & 7, hr = (b >> 3) & 3, qgr = b >> 5;
  const int qg = 63 - qgr;                 // descending work length
  const int head = kvg * 4 + hr;
  const int qrow = qg * 32 + q31;

  // Q fragments (B-operand: col q = lane&31, k = hi*8 + j), SCALE pre-folded by ropek
  u16x8 qf[8];
#pragma unroll
  for (int kc = 0; kc < 8; ++kc)
    qf[kc] = *(const u16x8*)&Q[(size_t)qrow * 4096 + head * 128 + kc * 16 + hi * 8];

  f32x16 accO[4];
#pragma unroll
  for (int f = 0; f < 4; ++f)
#pragma unroll
    for (int r = 0; r < 16; ++r) accO[f][r] = 0.f;
  float m_run = -1e30f, l_run = 0.f;

  for (int kvt = 0; kvt <= qg; ++kvt) {
    // K A-fragments: row key = lane&31, k = hd chunk
    const unsigned short* Kbase = KV + (size_t)(kvt * 32 + q31) * 2048 + kvg * 128 + hi * 8;
    u16x8 kf[8];
#pragma unroll
    for (int kc = 0; kc < 8; ++kc) kf[kc] = *(const u16x8*)(Kbase + kc * 16);

    f32x16 s;
#pragma unroll
    for (int r = 0; r < 16; ++r) s[r] = 0.f;
#pragma unroll
    for (int kc = 0; kc < 8; ++kc) s = mfma32(kf[kc], qf[kc], s);

    // causal mask on the diagonal tile; key(reg,hi) = (reg&3) + 8*(reg>>2) + 4*hi
    if (kvt == qg) {
#pragma unroll
      for (int r = 0; r < 16; ++r) {
        int key = (r & 3) + 8 * (r >> 2) + 4 * hi;
        if (key > q31) s[r] = -1e30f;
      }
    }

    // per-q (per-lane) online softmax; lanes l and l+32 jointly hold the 32 keys
    float pm = s[0];
#pragma unroll
    for (int r = 1; r < 16; ++r) pm = fmaxf(pm, s[r]);
    pm = fmaxf(pm, __shfl_xor(pm, 32, 64));
    if (!__all(pm - m_run <= 8.f)) {  // T13 defer-max
      float mn = fmaxf(m_run, pm);
      float al = __expf(m_run - mn);
      m_run = mn;
      l_run *= al;
#pragma unroll
      for (int f = 0; f < 4; ++f)
#pragma unroll
        for (int r = 0; r < 16; ++r) accO[f][r] *= al;
    }
    float p[16], ls = 0.f;
#pragma unroll
    for (int r = 0; r < 16; ++r) { p[r] = __expf(s[r] - m_run); ls += p[r]; }
    l_run += ls + __shfl_xor(ls, 32, 64);

    // pack P to bf16 pairs; w[i] holds keys (2i,2i+1 of this lane's set)
    unsigned int w[8], wp[8];
#pragma unroll
    for (int i = 0; i < 8; ++i) w[i] = cvtpk(p[2 * i], p[2 * i + 1]);
#pragma unroll
    for (int i = 0; i < 8; ++i) wp[i] = (unsigned int)__shfl_xor((int)w[i], 32, 64);
    // B-frag (col q = lane&31, k = keys ks*16 + hi*8 + j):
    //  ks0: hi=0 -> {w0,w1,wp0,wp1}; hi=1 -> {wp2,wp3,w2,w3}
    //  ks1: hi=0 -> {w4,w5,wp4,wp5}; hi=1 -> {wp6,wp7,w6,w7}
    union { unsigned int u[4]; u16x8 v; } pf0, pf1;
    pf0.u[0] = hi ? wp[2] : w[0];
    pf0.u[1] = hi ? wp[3] : w[1];
    pf0.u[2] = hi ? w[2] : wp[0];
    pf0.u[3] = hi ? w[3] : wp[1];
    pf1.u[0] = hi ? wp[6] : w[4];
    pf1.u[1] = hi ? wp[7] : w[5];
    pf1.u[2] = hi ? w[6] : wp[4];
    pf1.u[3] = hi ? w[7] : wp[5];

    // PV: accO[f] (C rows = hd f*32+..., cols = q) += V^T-frag * P-frag
    const unsigned short* Vbase = Vt + (size_t)(kvg * 128 + q31) * 2048 + kvt * 32 + hi * 8;
#pragma unroll
    for (int f = 0; f < 4; ++f) {
      u16x8 vf0 = *(const u16x8*)(Vbase + (size_t)f * 32 * 2048);
      u16x8 vf1 = *(const u16x8*)(Vbase + (size_t)f * 32 * 2048 + 16);
      accO[f] = mfma32(vf0, pf0.v, accO[f]);
      accO[f] = mfma32(vf1, pf1.v, accO[f]);
    }
  }

  // epilogue: hd = f*32 + (reg&3) + 8*(reg>>2) + 4*hi; regs 4g..4g+3 are consecutive hd
  float linv = 1.0f / l_run;
  unsigned short* orow = Ao + (size_t)qrow * 4096 + head * 128;
#pragma unroll
  for (int f = 0; f < 4; ++f)
#pragma unroll
    for (int g4 = 0; g4 < 4; ++g4) {
      unsigned int lo = (unsigned int)f2bf(accO[f][g4 * 4 + 0] * linv) |
                        ((unsigned int)f2bf(accO[f][g4 * 4 + 1] * linv) << 16);
      unsigned int hi2 = (unsigned int)f2bf(accO[f][g4 * 4 + 2] * linv) |
                         ((unsigned int)f2bf(accO[f][g4 * 4 + 3] * linv) << 16);
      *(uint2*)(orow + f * 32 + 8 * g4 + 4 * hi) = make_uint2(lo, hi2);
    }
}

extern "C" void kernel_launch(void* const* d_in, const int* in_sizes, int n_in,
                              void* d_out, int out_size, void* d_ws, size_t ws_size,
                              hipStream_t stream) {
  (void)in_sizes; (void)n_in; (void)out_size; (void)ws_size;
  const float* x  = (const float*)d_in[0];
  const float* fc = (const float*)d_in[1];
  // d_in[2] = mask: exactly triu(-1e9, k=1) -> causal handled in-kernel
  const float* wq = (const float*)d_in[3];
  const float* wk = (const float*)d_in[4];
  const float* wv = (const float*)d_in[5];
  const float* wo = (const float*)d_in[6];

  unsigned short* xb   = (unsigned short*)d_ws;
  unsigned short* wqb  = xb   + (size_t)8  * 1024 * 1024;
  unsigned short* wkvb = wqb  + (size_t)16 * 1024 * 1024;  // wk rows then wv rows
  unsigned short* wob  = wkvb + (size_t)8  * 1024 * 1024;
  unsigned short* Qb   = wob  + (size_t)16 * 1024 * 1024;
  unsigned short* KVb  = Qb   + (size_t)8  * 1024 * 1024;  // [s][0..1023]=K, [1024..2047]=V
  unsigned short* Vtb  = KVb  + (size_t)4  * 1024 * 1024;  // V^T [e][s]
  unsigned short* Ab   = Vtb  + (size_t)2  * 1024 * 1024;

  cvtk<<<dim3(8 * 1024 * 1024 / 1024), 256, 0, stream>>>(x, xb, 8 * 1024 * 1024);
  cvtk<<<dim3(16 * 1024 * 1024 / 1024), 256, 0, stream>>>(wq, wqb, 16 * 1024 * 1024);
  cvtk<<<dim3(4 * 1024 * 1024 / 1024), 256, 0, stream>>>(wk, wkvb, 4 * 1024 * 1024);
  cvtk<<<dim3(4 * 1024 * 1024 / 1024), 256, 0, stream>>>(wv, wkvb + (size_t)4 * 1024 * 1024,
                                                         4 * 1024 * 1024);
  cvtk<<<dim3(16 * 1024 * 1024 / 1024), 256, 0, stream>>>(wo, wob, 16 * 1024 * 1024);

  gemm_bt<1><<<dim3(4096 / 128, 2048 / 128), 256, 0, stream>>>(xb, wqb, Qb, 2048, 4096, 4096);
  gemm_bt<1><<<dim3(2048 / 128, 2048 / 128), 256, 0, stream>>>(xb, wkvb, KVb, 2048, 2048, 4096);

  ropek<<<dim3(2048 * 32 * 64 / 256), 256, 0, stream>>>(Qb, fc, 5, 4096, SCALE_F);
  ropek<<<dim3(2048 * 8 * 64 / 256), 256, 0, stream>>>(KVb, fc, 3, 2048, 1.0f);
  transpV<<<dim3(32, 64), dim3(32, 8), 0, stream>>>(KVb, Vtb);

  attnk<<<dim3(2048), 64, 0, stream>>>(Qb, KVb, Vtb, Ab);

  gemm_bt<0><<<dim3(4096 / 128, 2048 / 128), 256, 0, stream>>>(Ab, wob, d_out, 2048, 4096, 4096);
}

// Round 3
// 476.397 us; speedup vs baseline: 1.2136x; 1.1235x over previous
//
#include <hip/hip_runtime.h>
#include <stdint.h>

// Problem constants: B=1, S=2048, D=4096, H=32, KV=8, HD=128, NREP=4
#define SCALE_F 0.08838834764831845f
#define LOG2E_F 1.4426950408889634f

typedef __bf16 bf16x8_t __attribute__((ext_vector_type(8)));
typedef unsigned short u16x8 __attribute__((ext_vector_type(8)));
typedef float f32x4 __attribute__((ext_vector_type(4)));
typedef float f32x16 __attribute__((ext_vector_type(16)));

__device__ __forceinline__ unsigned short f2bf(float f) {
  unsigned int u = __float_as_uint(f);
  unsigned int r = ((u >> 16) & 1u) + 0x7FFFu;  // RNE
  return (unsigned short)((u + r) >> 16);
}
__device__ __forceinline__ float bf2f(unsigned short s) {
  return __uint_as_float(((unsigned int)s) << 16);
}
__device__ __forceinline__ f32x4 mfma16(u16x8 a, u16x8 b, f32x4 c) {
  return __builtin_amdgcn_mfma_f32_16x16x32_bf16(
      __builtin_bit_cast(bf16x8_t, a), __builtin_bit_cast(bf16x8_t, b), c, 0, 0, 0);
}
__device__ __forceinline__ f32x16 mfma32(u16x8 a, u16x8 b, f32x16 c) {
  return __builtin_amdgcn_mfma_f32_32x32x16_bf16(
      __builtin_bit_cast(bf16x8_t, a), __builtin_bit_cast(bf16x8_t, b), c, 0, 0, 0);
}
__device__ __forceinline__ unsigned int cvtpk(float lo, float hi) {
  unsigned int r;
  asm("v_cvt_pk_bf16_f32 %0, %1, %2" : "=v"(r) : "v"(lo), "v"(hi));
  return r;
}
__device__ __forceinline__ float exp2_hw(float x) {  // D = 2^S0
  float r;
  asm("v_exp_f32 %0, %1" : "=v"(r) : "v"(x));
  return r;
}
__device__ __forceinline__ void gload_lds16(const void* g, void* l) {
  __builtin_amdgcn_global_load_lds((const __attribute__((address_space(1))) void*)g,
                                   (__attribute__((address_space(3))) void*)l, 16, 0, 0);
}

// ---------------- f32 -> bf16 convert ----------------
__global__ void cvtk(const float* __restrict__ in, unsigned short* __restrict__ out, int n) {
  int i = (blockIdx.x * blockDim.x + threadIdx.x) * 4;
  if (i >= n) return;
  float4 v = *(const float4*)(in + i);
  unsigned int p0 = (unsigned int)f2bf(v.x) | ((unsigned int)f2bf(v.y) << 16);
  unsigned int p1 = (unsigned int)f2bf(v.z) | ((unsigned int)f2bf(v.w) << 16);
  *(uint2*)(out + i) = make_uint2(p0, p1);
}

// ---------------- RoPE for Q in place (folds SCALE*log2e) ----------------
__global__ void ropek(unsigned short* __restrict__ buf, const float* __restrict__ fc,
                      int hshift, int rowstride, float scale) {
  int idx = blockIdx.x * blockDim.x + threadIdx.x;  // over S * nH * 64
  int j = idx & 63;
  int h = (idx >> 6) & ((1 << hshift) - 1);
  int s = idx >> (6 + hshift);
  unsigned short* p = buf + (size_t)s * rowstride + h * 128 + 2 * j;
  float cs = fc[(s * 64 + j) * 2];
  float sn = fc[(s * 64 + j) * 2 + 1];
  float a = bf2f(p[0]), b = bf2f(p[1]);
  unsigned int o0 = f2bf((a * cs - b * sn) * scale);
  unsigned int o1 = f2bf((a * sn + b * cs) * scale);
  *(unsigned int*)p = o0 | (o1 << 16);
}

// ---------------- K: RoPE + retile into chunk-transposed tile images ----------------
// Ktil[kvg][kvt] = 8KB tile of 512 x 16B chunks, chunk c = s*32 + r:
//   chunk(s, r) = K[key = kvt*32 + r][hd = s*8 .. s*8+7] (roped), for kv head kvg.
__global__ void ktile(const unsigned short* __restrict__ KVb, const float* __restrict__ fc,
                      unsigned short* __restrict__ Ktil) {
  int b = blockIdx.x;  // kvg*64 + kvt
  int kvg = b >> 6, kvt = b & 63;
  int tid = threadIdx.x;
#pragma unroll
  for (int cc = 0; cc < 2; ++cc) {
    int c = tid + cc * 256;
    int s = c >> 5, r = c & 31;
    int key = kvt * 32 + r;
    u16x8 v = *(const u16x8*)&KVb[(size_t)key * 2048 + kvg * 128 + s * 8];
    unsigned int o[4];
#pragma unroll
    for (int t = 0; t < 4; ++t) {
      int m = s * 4 + t;  // rope pair index 0..63
      float cs = fc[(key * 64 + m) * 2];
      float sn = fc[(key * 64 + m) * 2 + 1];
      float a = bf2f((unsigned short)v[2 * t]), bb = bf2f((unsigned short)v[2 * t + 1]);
      o[t] = (unsigned int)f2bf(a * cs - bb * sn) | ((unsigned int)f2bf(a * sn + bb * cs) << 16);
    }
    *(uint4*)&Ktil[(size_t)b * 4096 + c * 8] = make_uint4(o[0], o[1], o[2], o[3]);
  }
}

// ---------------- V: transpose + retile ----------------
// Vtil[kvg][kvt] = 8KB of 512 chunks, chunk c = v*128 + hd:
//   chunk(v, hd) = V[key = kvt*32 + v*8 + t][hd], t=0..7  (i.e. V^T 8-key granules)
__global__ void vtile(const unsigned short* __restrict__ KVb, unsigned short* __restrict__ Vtil) {
  int b = blockIdx.x;  // kvg*64 + kvt
  int kvg = b >> 6, kvt = b & 63;
  int tid = threadIdx.x;
#pragma unroll
  for (int cc = 0; cc < 2; ++cc) {
    int c = tid + cc * 256;
    int v = c >> 7, hd = c & 127;
    unsigned short o[8];
#pragma unroll
    for (int t = 0; t < 8; ++t)
      o[t] = KVb[(size_t)(kvt * 32 + v * 8 + t) * 2048 + 1024 + kvg * 128 + hd];
    *(uint4*)&Vtil[(size_t)b * 4096 + c * 8] = *(uint4*)o;
  }
}

// ---------------- bf16 GEMM: C[M][N] = A[M][K] * BT[N][K]^T  (m97 structure) ----------------
template <int OUTBF16>
__global__ __launch_bounds__(256) void gemm_bt(const unsigned short* __restrict__ A,
                                               const unsigned short* __restrict__ BT,
                                               void* __restrict__ Cout, int M, int N, int K) {
  __shared__ __align__(16) unsigned short Atile[128 * 32];
  __shared__ __align__(16) unsigned short Btile[128 * 32];
  const int tid = threadIdx.x;
  const int w = tid >> 6, l = tid & 63;
  const int c = l & 15, h = l >> 4;
  const int m0 = blockIdx.y * 128, n0 = blockIdx.x * 128;
  const int wr = (w >> 1) * 64, wc = (w & 1) * 64;
  f32x4 acc[4][4];
#pragma unroll
  for (int mf = 0; mf < 4; ++mf)
#pragma unroll
    for (int nf = 0; nf < 4; ++nf)
#pragma unroll
      for (int r = 0; r < 4; ++r) acc[mf][nf][r] = 0.f;

  const int nk = K >> 5;
  for (int kt = 0; kt < nk; ++kt) {
    __syncthreads();
    const int kb = kt * 32;
#pragma unroll
    for (int i = 0; i < 4; ++i) {
      int chunk = w * 4 + i;              // 0..7 -> A, 8..15 -> B
      int eoff = (chunk & 7) * 512 + l * 8;
      int row = eoff >> 5, col = eoff & 31;
      const unsigned short* gsrc = (chunk & 8)
          ? (BT + (size_t)(n0 + row) * K + kb + col)
          : (A + (size_t)(m0 + row) * K + kb + col);
      unsigned short* ldst = ((chunk & 8) ? Btile : Atile) + eoff;
      gload_lds16(gsrc, ldst);
    }
    __syncthreads();
    u16x8 af[4], bfr[4];
#pragma unroll
    for (int mf = 0; mf < 4; ++mf)
      af[mf] = *(const u16x8*)&Atile[(wr + mf * 16 + c) * 32 + h * 8];
#pragma unroll
    for (int nf = 0; nf < 4; ++nf)
      bfr[nf] = *(const u16x8*)&Btile[(wc + nf * 16 + c) * 32 + h * 8];
#pragma unroll
    for (int mf = 0; mf < 4; ++mf)
#pragma unroll
      for (int nf = 0; nf < 4; ++nf)
        acc[mf][nf] = mfma16(af[mf], bfr[nf], acc[mf][nf]);
  }
  // epilogue: C/D layout col=lane&15, row=(lane>>4)*4+r  [m89-verified]
#pragma unroll
  for (int mf = 0; mf < 4; ++mf)
#pragma unroll
    for (int nf = 0; nf < 4; ++nf)
#pragma unroll
      for (int r = 0; r < 4; ++r) {
        int row = m0 + wr + mf * 16 + h * 4 + r;
        int col = n0 + wc + nf * 16 + c;
        float v = acc[mf][nf][r];
        if (OUTBF16)
          ((unsigned short*)Cout)[(size_t)row * N + col] = f2bf(v);
        else
          ((float*)Cout)[(size_t)row * N + col] = v;
      }
}

// ---------------- flash attention (causal GQA), 32x32x16 swapped-MFMA ----------------
// Block = 4 waves = 4 heads of one kv-group sharing K/V LDS tiles; wave owns 32 q-rows.
// S = mfma(K,Q): lane owns q-col -> in-lane softmax (exp2 domain; log2e folded into Q).
// K/V tiles staged linearly (pre-tiled global images) with double buffer + counted vmcnt.
__global__ __launch_bounds__(256) void attnk(const unsigned short* __restrict__ Q,
                                             const unsigned short* __restrict__ Ktil,
                                             const unsigned short* __restrict__ Vtil,
                                             unsigned short* __restrict__ Ao) {
  __shared__ __align__(16) unsigned short Kbuf[2][4096];  // 8KB per buffer
  __shared__ __align__(16) unsigned short Vbuf[2][4096];
  const int tid = threadIdx.x;
  const int w = tid >> 6, l = tid & 63;
  const int q31 = l & 31, hi = l >> 5;
  const int b = blockIdx.x;
  const int kvg = b & 7;             // kv-group -> XCD affinity (b%8 round-robin)
  const int qg = 63 - (b >> 3);      // descending work length for backfill balance
  const int head = kvg * 4 + w;
  const int qrow = qg * 32 + q31;

  // Q fragments (B-operand: col q = lane&31, k = hi*8 + j); SCALE*log2e pre-folded
  u16x8 qf[8];
#pragma unroll
  for (int kc = 0; kc < 8; ++kc)
    qf[kc] = *(const u16x8*)&Q[(size_t)qrow * 4096 + head * 128 + kc * 16 + hi * 8];

  f32x16 accO[4];
#pragma unroll
  for (int f = 0; f < 4; ++f)
#pragma unroll
    for (int r = 0; r < 16; ++r) accO[f][r] = 0.f;
  float m_run = -1e30f, l_run = 0.f;

  const unsigned short* ktb = Ktil + (size_t)kvg * 64 * 4096;
  const unsigned short* vtb = Vtil + (size_t)kvg * 64 * 4096;
  auto STAGE = [&](int d, int t) {
    const unsigned short* ks = ktb + (size_t)t * 4096 + w * 1024 + l * 8;
    const unsigned short* vs = vtb + (size_t)t * 4096 + w * 1024 + l * 8;
    gload_lds16(ks, &Kbuf[d][w * 1024 + l * 8]);
    gload_lds16(ks + 512, &Kbuf[d][w * 1024 + 512 + l * 8]);
    gload_lds16(vs, &Vbuf[d][w * 1024 + l * 8]);
    gload_lds16(vs + 512, &Vbuf[d][w * 1024 + 512 + l * 8]);
  };

  STAGE(0, 0);
  int cur = 0;
  for (int kvt = 0; kvt <= qg; ++kvt) {
    __builtin_amdgcn_s_barrier();          // all waves done reading buf[cur^1]
    __builtin_amdgcn_sched_barrier(0);
    if (kvt < qg) {
      STAGE(cur ^ 1, kvt + 1);
      asm volatile("s_waitcnt vmcnt(4)" ::: "memory");  // tile kvt landed; next 4 in flight
    } else {
      asm volatile("s_waitcnt vmcnt(0)" ::: "memory");
    }
    __builtin_amdgcn_s_barrier();          // everyone's tile-kvt loads landed
    __builtin_amdgcn_sched_barrier(0);

    // S = Q K^T : conflict-free ds_read_b128 (64 consecutive chunks per instr)
    f32x16 s;
#pragma unroll
    for (int r = 0; r < 16; ++r) s[r] = 0.f;
#pragma unroll
    for (int kc = 0; kc < 8; ++kc) {
      u16x8 kf = *(const u16x8*)&Kbuf[cur][((2 * kc + hi) * 32 + q31) * 8];
      s = mfma32(kf, qf[kc], s);
    }

    // causal mask on diagonal tile; key(reg,hi) = (reg&3) + 8*(reg>>2) + 4*hi
    if (kvt == qg) {
#pragma unroll
      for (int r = 0; r < 16; ++r) {
        int key = (r & 3) + 8 * (r >> 2) + 4 * hi;
        if (key > q31) s[r] = -1e30f;
      }
    }

    // in-lane online softmax (log2 domain); lanes l, l+32 jointly hold 32 keys
    float pm = s[0];
#pragma unroll
    for (int r = 1; r < 16; ++r) pm = fmaxf(pm, s[r]);
    pm = fmaxf(pm, __shfl_xor(pm, 32, 64));
    if (!__all(pm - m_run <= 8.f)) {  // T13 defer-max (2^8 bound)
      float mn = fmaxf(m_run, pm);
      float al = exp2_hw(m_run - mn);
      m_run = mn;
      l_run *= al;
#pragma unroll
      for (int f = 0; f < 4; ++f)
#pragma unroll
        for (int r = 0; r < 16; ++r) accO[f][r] *= al;
    }
    float p[16], ls = 0.f;
#pragma unroll
    for (int r = 0; r < 16; ++r) { p[r] = exp2_hw(s[r] - m_run); ls += p[r]; }
    l_run += ls + __shfl_xor(ls, 32, 64);

    // pack P -> bf16 B-fragments (layout validated in round 2)
    unsigned int wv[8], wp[8];
#pragma unroll
    for (int i = 0; i < 8; ++i) wv[i] = cvtpk(p[2 * i], p[2 * i + 1]);
#pragma unroll
    for (int i = 0; i < 8; ++i) wp[i] = (unsigned int)__shfl_xor((int)wv[i], 32, 64);
    union { unsigned int u[4]; u16x8 v; } pf0, pf1;
    pf0.u[0] = hi ? wp[2] : wv[0];
    pf0.u[1] = hi ? wp[3] : wv[1];
    pf0.u[2] = hi ? wv[2] : wp[0];
    pf0.u[3] = hi ? wv[3] : wp[1];
    pf1.u[0] = hi ? wp[6] : wv[4];
    pf1.u[1] = hi ? wp[7] : wv[5];
    pf1.u[2] = hi ? wv[6] : wp[4];
    pf1.u[3] = hi ? wv[7] : wp[5];

    // PV: accO[f] += V^T-frag * P-frag (conflict-free chunk reads)
#pragma unroll
    for (int f = 0; f < 4; ++f) {
      u16x8 vf0 = *(const u16x8*)&Vbuf[cur][((hi) * 128 + f * 32 + q31) * 8];
      u16x8 vf1 = *(const u16x8*)&Vbuf[cur][((2 + hi) * 128 + f * 32 + q31) * 8];
      accO[f] = mfma32(vf0, pf0.v, accO[f]);
      accO[f] = mfma32(vf1, pf1.v, accO[f]);
    }
    cur ^= 1;
  }

  // epilogue: hd = f*32 + (reg&3) + 8*(reg>>2) + 4*hi
  float linv = 1.0f / l_run;
  unsigned short* orow = Ao + (size_t)qrow * 4096 + head * 128;
#pragma unroll
  for (int f = 0; f < 4; ++f)
#pragma unroll
    for (int g4 = 0; g4 < 4; ++g4) {
      unsigned int lo = (unsigned int)f2bf(accO[f][g4 * 4 + 0] * linv) |
                        ((unsigned int)f2bf(accO[f][g4 * 4 + 1] * linv) << 16);
      unsigned int hi2 = (unsigned int)f2bf(accO[f][g4 * 4 + 2] * linv) |
                         ((unsigned int)f2bf(accO[f][g4 * 4 + 3] * linv) << 16);
      *(uint2*)(orow + f * 32 + 8 * g4 + 4 * hi) = make_uint2(lo, hi2);
    }
}

extern "C" void kernel_launch(void* const* d_in, const int* in_sizes, int n_in,
                              void* d_out, int out_size, void* d_ws, size_t ws_size,
                              hipStream_t stream) {
  (void)in_sizes; (void)n_in; (void)out_size; (void)ws_size;
  const float* x  = (const float*)d_in[0];
  const float* fc = (const float*)d_in[1];
  // d_in[2] = mask: exactly triu(-1e9, k=1) -> causal handled in-kernel
  const float* wq = (const float*)d_in[3];
  const float* wk = (const float*)d_in[4];
  const float* wv = (const float*)d_in[5];
  const float* wo = (const float*)d_in[6];

  const size_t M = 1024 * 1024;
  unsigned short* xb   = (unsigned short*)d_ws;      // 8M shorts; reused as Ab after GEMMs
  unsigned short* wqb  = xb   + 8 * M;               // 16M
  unsigned short* wkvb = wqb  + 16 * M;              // 8M (wk rows then wv rows)
  unsigned short* wob  = wkvb + 8 * M;               // 16M
  unsigned short* Qb   = wob  + 16 * M;              // 8M
  unsigned short* KVb  = Qb   + 8 * M;               // 4M  [s][0..1023]=K, [1024..2047]=V
  unsigned short* Ktil = KVb  + 4 * M;               // 2M  tiled+roped K images
  unsigned short* Vtil = Ktil + 2 * M;               // 2M  tiled V^T images
  unsigned short* Ab   = xb;                         // alias: xb dead after KV GEMM

  cvtk<<<dim3(8 * M / 1024), 256, 0, stream>>>(x, xb, 8 * M);
  cvtk<<<dim3(16 * M / 1024), 256, 0, stream>>>(wq, wqb, 16 * M);
  cvtk<<<dim3(4 * M / 1024), 256, 0, stream>>>(wk, wkvb, 4 * M);
  cvtk<<<dim3(4 * M / 1024), 256, 0, stream>>>(wv, wkvb + 4 * M, 4 * M);
  cvtk<<<dim3(16 * M / 1024), 256, 0, stream>>>(wo, wob, 16 * M);

  gemm_bt<1><<<dim3(4096 / 128, 2048 / 128), 256, 0, stream>>>(xb, wqb, Qb, 2048, 4096, 4096);
  gemm_bt<1><<<dim3(2048 / 128, 2048 / 128), 256, 0, stream>>>(xb, wkvb, KVb, 2048, 2048, 4096);

  ropek<<<dim3(2048 * 32 * 64 / 256), 256, 0, stream>>>(Qb, fc, 5, 4096, SCALE_F * LOG2E_F);
  ktile<<<dim3(512), 256, 0, stream>>>(KVb, fc, Ktil);
  vtile<<<dim3(512), 256, 0, stream>>>(KVb, Vtil);

  attnk<<<dim3(512), 256, 0, stream>>>(Qb, Ktil, Vtil, Ab);

  gemm_bt<0><<<dim3(4096 / 128, 2048 / 128), 256, 0, stream>>>(Ab, wob, d_out, 2048, 4096, 4096);
}

// Round 4
// 411.861 us; speedup vs baseline: 1.4038x; 1.1567x over previous
//
#include <hip/hip_runtime.h>
#include <stdint.h>

// Problem constants: B=1, S=2048, D=4096, H=32, KV=8, HD=128, NREP=4
#define SCALE_F 0.08838834764831845f
#define LOG2E_F 1.4426950408889634f

typedef __bf16 bf16x8_t __attribute__((ext_vector_type(8)));
typedef unsigned short u16x8 __attribute__((ext_vector_type(8)));
typedef float f32x4 __attribute__((ext_vector_type(4)));
typedef float f32x16 __attribute__((ext_vector_type(16)));

__device__ __forceinline__ unsigned short f2bf(float f) {
  unsigned int u = __float_as_uint(f);
  unsigned int r = ((u >> 16) & 1u) + 0x7FFFu;  // RNE
  return (unsigned short)((u + r) >> 16);
}
__device__ __forceinline__ float bf2f(unsigned short s) {
  return __uint_as_float(((unsigned int)s) << 16);
}
__device__ __forceinline__ f32x4 mfma16(u16x8 a, u16x8 b, f32x4 c) {
  return __builtin_amdgcn_mfma_f32_16x16x32_bf16(
      __builtin_bit_cast(bf16x8_t, a), __builtin_bit_cast(bf16x8_t, b), c, 0, 0, 0);
}
__device__ __forceinline__ f32x16 mfma32(u16x8 a, u16x8 b, f32x16 c) {
  return __builtin_amdgcn_mfma_f32_32x32x16_bf16(
      __builtin_bit_cast(bf16x8_t, a), __builtin_bit_cast(bf16x8_t, b), c, 0, 0, 0);
}
__device__ __forceinline__ unsigned int cvtpk(float lo, float hi) {
  unsigned int r;
  asm("v_cvt_pk_bf16_f32 %0, %1, %2" : "=v"(r) : "v"(lo), "v"(hi));
  return r;
}
__device__ __forceinline__ float exp2_hw(float x) {  // D = 2^S0
  float r;
  asm("v_exp_f32 %0, %1" : "=v"(r) : "v"(x));
  return r;
}
__device__ __forceinline__ void gload_lds16(const void* g, void* l) {
  __builtin_amdgcn_global_load_lds((const __attribute__((address_space(1))) void*)g,
                                   (__attribute__((address_space(3))) void*)l, 16, 0, 0);
}

// ---------------- f32 -> bf16 convert ----------------
__global__ void cvtk(const float* __restrict__ in, unsigned short* __restrict__ out, int n) {
  int i = (blockIdx.x * blockDim.x + threadIdx.x) * 4;
  if (i >= n) return;
  float4 v = *(const float4*)(in + i);
  unsigned int p0 = (unsigned int)f2bf(v.x) | ((unsigned int)f2bf(v.y) << 16);
  unsigned int p1 = (unsigned int)f2bf(v.z) | ((unsigned int)f2bf(v.w) << 16);
  *(uint2*)(out + i) = make_uint2(p0, p1);
}

// ---------------- RoPE for Q in place (folds SCALE*log2e) ----------------
__global__ void ropek(unsigned short* __restrict__ buf, const float* __restrict__ fc,
                      int hshift, int rowstride, float scale) {
  int idx = blockIdx.x * blockDim.x + threadIdx.x;  // over S * nH * 64
  int j = idx & 63;
  int h = (idx >> 6) & ((1 << hshift) - 1);
  int s = idx >> (6 + hshift);
  unsigned short* p = buf + (size_t)s * rowstride + h * 128 + 2 * j;
  float cs = fc[(s * 64 + j) * 2];
  float sn = fc[(s * 64 + j) * 2 + 1];
  float a = bf2f(p[0]), b = bf2f(p[1]);
  unsigned int o0 = f2bf((a * cs - b * sn) * scale);
  unsigned int o1 = f2bf((a * sn + b * cs) * scale);
  *(unsigned int*)p = o0 | (o1 << 16);
}

// ---------------- K: RoPE + retile into chunk-transposed tile images ----------------
// Ktil[kvg][kvt] = 8KB tile of 512 x 16B chunks, chunk c = s*32 + r:
//   chunk(s, r) = K[key = kvt*32 + r][hd = s*8 .. s*8+7] (roped), for kv head kvg.
// K lives in QKV at col offset 4096 + kvg*128, row stride 6144.
__global__ void ktile(const unsigned short* __restrict__ QKV, const float* __restrict__ fc,
                      unsigned short* __restrict__ Ktil) {
  int b = blockIdx.x;  // kvg*64 + kvt
  int kvg = b >> 6, kvt = b & 63;
  int tid = threadIdx.x;
#pragma unroll
  for (int cc = 0; cc < 2; ++cc) {
    int c = tid + cc * 256;
    int s = c >> 5, r = c & 31;
    int key = kvt * 32 + r;
    u16x8 v = *(const u16x8*)&QKV[(size_t)key * 6144 + 4096 + kvg * 128 + s * 8];
    unsigned int o[4];
#pragma unroll
    for (int t = 0; t < 4; ++t) {
      int m = s * 4 + t;  // rope pair index 0..63
      float cs = fc[(key * 64 + m) * 2];
      float sn = fc[(key * 64 + m) * 2 + 1];
      float a = bf2f((unsigned short)v[2 * t]), bb = bf2f((unsigned short)v[2 * t + 1]);
      o[t] = (unsigned int)f2bf(a * cs - bb * sn) | ((unsigned int)f2bf(a * sn + bb * cs) << 16);
    }
    *(uint4*)&Ktil[(size_t)b * 4096 + c * 8] = make_uint4(o[0], o[1], o[2], o[3]);
  }
}

// ---------------- V: transpose + retile ----------------
// Vtil[kvg][kvt] = 8KB of 512 chunks, chunk c = v*128 + hd:
//   chunk(v, hd) = V[key = kvt*32 + v*8 + t][hd], t=0..7  (V^T 8-key granules)
__global__ void vtile(const unsigned short* __restrict__ QKV, unsigned short* __restrict__ Vtil) {
  int b = blockIdx.x;  // kvg*64 + kvt
  int kvg = b >> 6, kvt = b & 63;
  int tid = threadIdx.x;
#pragma unroll
  for (int cc = 0; cc < 2; ++cc) {
    int c = tid + cc * 256;
    int v = c >> 7, hd = c & 127;
    unsigned short o[8];
#pragma unroll
    for (int t = 0; t < 8; ++t)
      o[t] = QKV[(size_t)(kvt * 32 + v * 8 + t) * 6144 + 5120 + kvg * 128 + hd];
    *(uint4*)&Vtil[(size_t)b * 4096 + c * 8] = *(uint4*)o;
  }
}

// ---------------- 256x256 8-phase bf16 GEMM: C[M][N] = A[M][K] * BT[N][K]^T ----------------
// 8 waves (2M x 4N), BK=64 split into 2 k-halves -> 4 phases/K-tile.
// LDS: 2 dbuf x (A 32KiB + B 32KiB), fragment-major chunk layout -> conflict-free b128
// reads AND linear global_load_lds staging (free permutation via source indexing).
// Pipeline: phase p stages 2 of tile t+1's 8 load-groups into the other buffer;
// vmcnt(4) at ends of odd phases guarantees the next consumption boundary. Race-free:
// buf e is only written after tile t-1's reads ended (end-of-tile barrier).
template <int OUTBF16>
__global__ __launch_bounds__(512, 2) void gemm8(const unsigned short* __restrict__ A,
                                                const unsigned short* __restrict__ BT,
                                                void* __restrict__ Cout,
                                                int M, int N, int K) {
  __shared__ __align__(16) unsigned short smem[65536];  // 128 KiB
  const int tid = threadIdx.x;
  const int w = tid >> 6, l = tid & 63;
  const int wm = w >> 2, wn = w & 3;
  const int c16 = l & 15, h4 = l >> 4;
  const int mt = M >> 8;
  const int cpx = (int)gridDim.x >> 3;
  const int wg = ((int)blockIdx.x & 7) * cpx + ((int)blockIdx.x >> 3);  // T1 XCD swizzle
  const int mi = wg % mt, ni = wg / mt;
  const int m0 = mi << 8, n0 = ni << 8;
  const int nt = K >> 6;

  // stage decode: part p (0..3) covers chunks c = p*512 + tid of a 2048-chunk image;
  // chunk c: kc=c>>10, F=(c>>6)&15, lane=c&63 -> row F*16+(lane&15), col kc*32+(lane>>4)*8
  int grow[4], gcol[4];
#pragma unroll
  for (int p = 0; p < 4; ++p) {
    int cc = p * 512 + tid;
    int ll = cc & 63, F = (cc >> 6) & 15, kc = cc >> 10;
    grow[p] = F * 16 + (ll & 15);
    gcol[p] = kc * 32 + ((ll >> 4) << 3);
  }
  auto stageA = [&](int e, int k0s, int p) {
    const unsigned short* src = A + (size_t)(m0 + grow[p]) * K + k0s + gcol[p];
    gload_lds16(src, &smem[e * 32768 + (p * 512 + tid) * 8]);
  };
  auto stageB = [&](int e, int k0s, int p) {
    const unsigned short* src = BT + (size_t)(n0 + grow[p]) * K + k0s + gcol[p];
    gload_lds16(src, &smem[e * 32768 + 16384 + (p * 512 + tid) * 8]);
  };

  f32x4 acc[2][4][4];
#pragma unroll
  for (int mh = 0; mh < 2; ++mh)
#pragma unroll
    for (int mf = 0; mf < 4; ++mf)
#pragma unroll
      for (int nf = 0; nf < 4; ++nf)
#pragma unroll
        for (int r = 0; r < 4; ++r) acc[mh][mf][nf][r] = 0.f;

  // prologue: tile 0 -> buf 0, issue order q0..q7 = A0,A1,B0,B1,A2,A3,B2,B3
  stageA(0, 0, 0); stageA(0, 0, 1); stageB(0, 0, 0); stageB(0, 0, 1);
  stageA(0, 0, 2); stageA(0, 0, 3); stageB(0, 0, 2); stageB(0, 0, 3);
  asm volatile("s_waitcnt vmcnt(4)" ::: "memory");
  __builtin_amdgcn_sched_barrier(0);
  asm volatile("s_barrier" ::: "memory");

  u16x8 bfr[4];
  for (int t = 0; t < nt; ++t) {
    const int d = t & 1, e = d ^ 1;
    const int dA = d * 32768, dB = dA + 16384;
    const int tsrc = (t + 1 < nt) ? t + 1 : t;  // clamp: redundant loads, never read
    const int ks = tsrc << 6;
#pragma unroll
    for (int p = 0; p < 4; ++p) {
      const int kc = p >> 1, mh = p & 1;
      u16x8 af[4];
#pragma unroll
      for (int mf = 0; mf < 4; ++mf)
        af[mf] = *(const u16x8*)&smem[dA + ((kc * 16 + wm * 8 + mh * 4 + mf) * 64 + l) * 8];
      if (mh == 0) {
#pragma unroll
        for (int nf = 0; nf < 4; ++nf)
          bfr[nf] = *(const u16x8*)&smem[dB + ((kc * 16 + wn * 4 + nf) * 64 + l) * 8];
      }
      if (p == 0)      { stageA(e, ks, 0); stageA(e, ks, 1); }
      else if (p == 1) { stageB(e, ks, 0); stageB(e, ks, 1); }
      else if (p == 2) { stageA(e, ks, 2); stageA(e, ks, 3); }
      else             { stageB(e, ks, 2); stageB(e, ks, 3); }
      asm volatile("s_barrier" ::: "memory");
      asm volatile("s_waitcnt lgkmcnt(0)" ::: "memory");
      __builtin_amdgcn_sched_barrier(0);
      __builtin_amdgcn_s_setprio(1);
#pragma unroll
      for (int mf = 0; mf < 4; ++mf)
#pragma unroll
        for (int nf = 0; nf < 4; ++nf)
          acc[mh][mf][nf] = mfma16(af[mf], bfr[nf], acc[mh][mf][nf]);
      __builtin_amdgcn_s_setprio(0);
      __builtin_amdgcn_sched_barrier(0);
      if (mh == 1) asm volatile("s_waitcnt vmcnt(4)" ::: "memory");
      asm volatile("s_barrier" ::: "memory");
    }
  }
  asm volatile("s_waitcnt vmcnt(0)" ::: "memory");  // drain clamp loads before endpgm

  // epilogue: C row = m0+wm*128+mh*64+mf*16+h4*4+r ; col = n0+wn*64+nf*16+c16
#pragma unroll
  for (int mh = 0; mh < 2; ++mh)
#pragma unroll
    for (int mf = 0; mf < 4; ++mf)
#pragma unroll
      for (int nf = 0; nf < 4; ++nf)
#pragma unroll
        for (int r = 0; r < 4; ++r) {
          int row = m0 + wm * 128 + mh * 64 + mf * 16 + h4 * 4 + r;
          int col = n0 + wn * 64 + nf * 16 + c16;
          float v = acc[mh][mf][nf][r];
          if (OUTBF16)
            ((unsigned short*)Cout)[(size_t)row * N + col] = f2bf(v);
          else
            ((float*)Cout)[(size_t)row * N + col] = v;
        }
}

// ---------------- flash attention (causal GQA), 32x32x16 swapped-MFMA ----------------
// Block = 4 waves = 4 heads of one kv-group sharing K/V LDS tiles; wave owns 32 q-rows.
__global__ __launch_bounds__(256) void attnk(const unsigned short* __restrict__ Q,
                                             const unsigned short* __restrict__ Ktil,
                                             const unsigned short* __restrict__ Vtil,
                                             unsigned short* __restrict__ Ao) {
  __shared__ __align__(16) unsigned short Kbuf[2][4096];  // 8KB per buffer
  __shared__ __align__(16) unsigned short Vbuf[2][4096];
  const int tid = threadIdx.x;
  const int w = tid >> 6, l = tid & 63;
  const int q31 = l & 31, hi = l >> 5;
  const int b = blockIdx.x;
  const int kvg = b & 7;             // kv-group -> XCD affinity
  const int qg = 63 - (b >> 3);      // descending work length for backfill balance
  const int head = kvg * 4 + w;
  const int qrow = qg * 32 + q31;

  // Q fragments (B-operand: col q = lane&31, k = hi*8 + j); SCALE*log2e pre-folded
  u16x8 qf[8];
#pragma unroll
  for (int kc = 0; kc < 8; ++kc)
    qf[kc] = *(const u16x8*)&Q[(size_t)qrow * 6144 + head * 128 + kc * 16 + hi * 8];

  f32x16 accO[4];
#pragma unroll
  for (int f = 0; f < 4; ++f)
#pragma unroll
    for (int r = 0; r < 16; ++r) accO[f][r] = 0.f;
  float m_run = -1e30f, l_run = 0.f;

  const unsigned short* ktb = Ktil + (size_t)kvg * 64 * 4096;
  const unsigned short* vtb = Vtil + (size_t)kvg * 64 * 4096;
  auto STAGE = [&](int d, int t) {
    const unsigned short* ks = ktb + (size_t)t * 4096 + w * 1024 + l * 8;
    const unsigned short* vs = vtb + (size_t)t * 4096 + w * 1024 + l * 8;
    gload_lds16(ks, &Kbuf[d][w * 1024 + l * 8]);
    gload_lds16(ks + 512, &Kbuf[d][w * 1024 + 512 + l * 8]);
    gload_lds16(vs, &Vbuf[d][w * 1024 + l * 8]);
    gload_lds16(vs + 512, &Vbuf[d][w * 1024 + 512 + l * 8]);
  };

  STAGE(0, 0);
  int cur = 0;
  for (int kvt = 0; kvt <= qg; ++kvt) {
    __builtin_amdgcn_s_barrier();          // all waves done reading buf[cur^1]
    __builtin_amdgcn_sched_barrier(0);
    if (kvt < qg) {
      STAGE(cur ^ 1, kvt + 1);
      asm volatile("s_waitcnt vmcnt(4)" ::: "memory");  // tile kvt landed
    } else {
      asm volatile("s_waitcnt vmcnt(0)" ::: "memory");
    }
    __builtin_amdgcn_s_barrier();          // everyone's tile-kvt loads landed
    __builtin_amdgcn_sched_barrier(0);

    // S = Q K^T : conflict-free ds_read_b128
    f32x16 s;
#pragma unroll
    for (int r = 0; r < 16; ++r) s[r] = 0.f;
#pragma unroll
    for (int kc = 0; kc < 8; ++kc) {
      u16x8 kf = *(const u16x8*)&Kbuf[cur][((2 * kc + hi) * 32 + q31) * 8];
      s = mfma32(kf, qf[kc], s);
    }

    // causal mask on diagonal tile; key(reg,hi) = (reg&3) + 8*(reg>>2) + 4*hi
    if (kvt == qg) {
#pragma unroll
      for (int r = 0; r < 16; ++r) {
        int key = (r & 3) + 8 * (r >> 2) + 4 * hi;
        if (key > q31) s[r] = -1e30f;
      }
    }

    // in-lane online softmax (log2 domain)
    float pm = s[0];
#pragma unroll
    for (int r = 1; r < 16; ++r) pm = fmaxf(pm, s[r]);
    pm = fmaxf(pm, __shfl_xor(pm, 32, 64));
    if (!__all(pm - m_run <= 8.f)) {  // T13 defer-max (2^8 bound)
      float mn = fmaxf(m_run, pm);
      float al = exp2_hw(m_run - mn);
      m_run = mn;
      l_run *= al;
#pragma unroll
      for (int f = 0; f < 4; ++f)
#pragma unroll
        for (int r = 0; r < 16; ++r) accO[f][r] *= al;
    }
    float p[16], ls = 0.f;
#pragma unroll
    for (int r = 0; r < 16; ++r) { p[r] = exp2_hw(s[r] - m_run); ls += p[r]; }
    l_run += ls + __shfl_xor(ls, 32, 64);

    // pack P -> bf16 B-fragments
    unsigned int wv[8], wp[8];
#pragma unroll
    for (int i = 0; i < 8; ++i) wv[i] = cvtpk(p[2 * i], p[2 * i + 1]);
#pragma unroll
    for (int i = 0; i < 8; ++i) wp[i] = (unsigned int)__shfl_xor((int)wv[i], 32, 64);
    union { unsigned int u[4]; u16x8 v; } pf0, pf1;
    pf0.u[0] = hi ? wp[2] : wv[0];
    pf0.u[1] = hi ? wp[3] : wv[1];
    pf0.u[2] = hi ? wv[2] : wp[0];
    pf0.u[3] = hi ? wv[3] : wp[1];
    pf1.u[0] = hi ? wp[6] : wv[4];
    pf1.u[1] = hi ? wp[7] : wv[5];
    pf1.u[2] = hi ? wv[6] : wp[4];
    pf1.u[3] = hi ? wv[7] : wp[5];

    // PV: accO[f] += V^T-frag * P-frag
#pragma unroll
    for (int f = 0; f < 4; ++f) {
      u16x8 vf0 = *(const u16x8*)&Vbuf[cur][((hi) * 128 + f * 32 + q31) * 8];
      u16x8 vf1 = *(const u16x8*)&Vbuf[cur][((2 + hi) * 128 + f * 32 + q31) * 8];
      accO[f] = mfma32(vf0, pf0.v, accO[f]);
      accO[f] = mfma32(vf1, pf1.v, accO[f]);
    }
    cur ^= 1;
  }

  // epilogue: hd = f*32 + (reg&3) + 8*(reg>>2) + 4*hi
  float linv = 1.0f / l_run;
  unsigned short* orow = Ao + (size_t)qrow * 4096 + head * 128;
#pragma unroll
  for (int f = 0; f < 4; ++f)
#pragma unroll
    for (int g4 = 0; g4 < 4; ++g4) {
      unsigned int lo = (unsigned int)f2bf(accO[f][g4 * 4 + 0] * linv) |
                        ((unsigned int)f2bf(accO[f][g4 * 4 + 1] * linv) << 16);
      unsigned int hi2 = (unsigned int)f2bf(accO[f][g4 * 4 + 2] * linv) |
                         ((unsigned int)f2bf(accO[f][g4 * 4 + 3] * linv) << 16);
      *(uint2*)(orow + f * 32 + 8 * g4 + 4 * hi) = make_uint2(lo, hi2);
    }
}

extern "C" void kernel_launch(void* const* d_in, const int* in_sizes, int n_in,
                              void* d_out, int out_size, void* d_ws, size_t ws_size,
                              hipStream_t stream) {
  (void)in_sizes; (void)n_in; (void)out_size; (void)ws_size;
  const float* x  = (const float*)d_in[0];
  const float* fc = (const float*)d_in[1];
  // d_in[2] = mask: exactly triu(-1e9, k=1) -> causal handled in-kernel
  const float* wq = (const float*)d_in[3];
  const float* wk = (const float*)d_in[4];
  const float* wv = (const float*)d_in[5];
  const float* wo = (const float*)d_in[6];

  const size_t M = 1024 * 1024;
  unsigned short* xb   = (unsigned short*)d_ws;      // 8M shorts; reused as Ab after GEMM1
  unsigned short* wfus = xb   + 8 * M;               // 24M: [wq 4096 | wk 1024 | wv 1024][4096]
  unsigned short* wob  = wfus + 24 * M;              // 16M
  unsigned short* QKV  = wob  + 16 * M;              // 12M: [2048][6144] = Q|K|V
  unsigned short* Ktil = QKV  + 12 * M;              // 2M  tiled+roped K images
  unsigned short* Vtil = Ktil + 2 * M;               // 2M  tiled V^T images
  unsigned short* Ab   = xb;                         // alias: xb dead after GEMM1

  cvtk<<<dim3(8 * M / 1024), 256, 0, stream>>>(x, xb, 8 * M);
  cvtk<<<dim3(16 * M / 1024), 256, 0, stream>>>(wq, wfus, 16 * M);
  cvtk<<<dim3(4 * M / 1024), 256, 0, stream>>>(wk, wfus + 16 * M, 4 * M);
  cvtk<<<dim3(4 * M / 1024), 256, 0, stream>>>(wv, wfus + 20 * M, 4 * M);
  cvtk<<<dim3(16 * M / 1024), 256, 0, stream>>>(wo, wob, 16 * M);

  // fused QKV projection: [2048][6144] = xb @ wfus^T   (192 blocks, nwg%8==0)
  gemm8<1><<<dim3(192), 512, 0, stream>>>(xb, wfus, QKV, 2048, 6144, 4096);

  ropek<<<dim3(2048 * 32 * 64 / 256), 256, 0, stream>>>(QKV, fc, 5, 6144, SCALE_F * LOG2E_F);
  ktile<<<dim3(512), 256, 0, stream>>>(QKV, fc, Ktil);
  vtile<<<dim3(512), 256, 0, stream>>>(QKV, Vtil);

  attnk<<<dim3(512), 256, 0, stream>>>(QKV, Ktil, Vtil, Ab);

  // output projection (128 blocks, nwg%8==0)
  gemm8<0><<<dim3(128), 512, 0, stream>>>(Ab, wob, d_out, 2048, 4096, 4096);
}

// Round 5
// 367.450 us; speedup vs baseline: 1.5735x; 1.1209x over previous
//
#include <hip/hip_runtime.h>
#include <stdint.h>

// Problem constants: B=1, S=2048, D=4096, H=32, KV=8, HD=128, NREP=4
#define SCALE_F 0.08838834764831845f
#define LOG2E_F 1.4426950408889634f

typedef __bf16 bf16x8_t __attribute__((ext_vector_type(8)));
typedef unsigned short u16x8 __attribute__((ext_vector_type(8)));
typedef float f32x4 __attribute__((ext_vector_type(4)));
typedef float f32x16 __attribute__((ext_vector_type(16)));

__device__ __forceinline__ unsigned short f2bf(float f) {
  unsigned int u = __float_as_uint(f);
  unsigned int r = ((u >> 16) & 1u) + 0x7FFFu;  // RNE
  return (unsigned short)((u + r) >> 16);
}
__device__ __forceinline__ float bf2f(unsigned short s) {
  return __uint_as_float(((unsigned int)s) << 16);
}
__device__ __forceinline__ f32x4 mfma16(u16x8 a, u16x8 b, f32x4 c) {
  return __builtin_amdgcn_mfma_f32_16x16x32_bf16(
      __builtin_bit_cast(bf16x8_t, a), __builtin_bit_cast(bf16x8_t, b), c, 0, 0, 0);
}
__device__ __forceinline__ f32x16 mfma32(u16x8 a, u16x8 b, f32x16 c) {
  return __builtin_amdgcn_mfma_f32_32x32x16_bf16(
      __builtin_bit_cast(bf16x8_t, a), __builtin_bit_cast(bf16x8_t, b), c, 0, 0, 0);
}
__device__ __forceinline__ unsigned int cvtpk(float lo, float hi) {
  unsigned int r;
  asm("v_cvt_pk_bf16_f32 %0, %1, %2" : "=v"(r) : "v"(lo), "v"(hi));
  return r;
}
__device__ __forceinline__ float exp2_hw(float x) {  // D = 2^S0
  float r;
  asm("v_exp_f32 %0, %1" : "=v"(r) : "v"(x));
  return r;
}
__device__ __forceinline__ void gload_lds16(const void* g, void* l) {
  __builtin_amdgcn_global_load_lds((const __attribute__((address_space(1))) void*)g,
                                   (__attribute__((address_space(3))) void*)l, 16, 0, 0);
}

// ---------------- f32 -> bf16 convert ----------------
__global__ void cvtk(const float* __restrict__ in, unsigned short* __restrict__ out, int n) {
  int i = (blockIdx.x * blockDim.x + threadIdx.x) * 4;
  if (i >= n) return;
  float4 v = *(const float4*)(in + i);
  unsigned int p0 = (unsigned int)f2bf(v.x) | ((unsigned int)f2bf(v.y) << 16);
  unsigned int p1 = (unsigned int)f2bf(v.z) | ((unsigned int)f2bf(v.w) << 16);
  *(uint2*)(out + i) = make_uint2(p0, p1);
}

// ---------------- RoPE for Q in place (folds SCALE*log2e) ----------------
__global__ void ropek(unsigned short* __restrict__ buf, const float* __restrict__ fc,
                      int hshift, int rowstride, float scale) {
  int idx = blockIdx.x * blockDim.x + threadIdx.x;  // over S * nH * 64
  int j = idx & 63;
  int h = (idx >> 6) & ((1 << hshift) - 1);
  int s = idx >> (6 + hshift);
  unsigned short* p = buf + (size_t)s * rowstride + h * 128 + 2 * j;
  float cs = fc[(s * 64 + j) * 2];
  float sn = fc[(s * 64 + j) * 2 + 1];
  float a = bf2f(p[0]), b = bf2f(p[1]);
  unsigned int o0 = f2bf((a * cs - b * sn) * scale);
  unsigned int o1 = f2bf((a * sn + b * cs) * scale);
  *(unsigned int*)p = o0 | (o1 << 16);
}

// ---------------- K: RoPE + retile into chunk-transposed tile images ----------------
__global__ void ktile(const unsigned short* __restrict__ QKV, const float* __restrict__ fc,
                      unsigned short* __restrict__ Ktil) {
  int b = blockIdx.x;  // kvg*64 + kvt
  int kvg = b >> 6, kvt = b & 63;
  int tid = threadIdx.x;
#pragma unroll
  for (int cc = 0; cc < 2; ++cc) {
    int c = tid + cc * 256;
    int s = c >> 5, r = c & 31;
    int key = kvt * 32 + r;
    u16x8 v = *(const u16x8*)&QKV[(size_t)key * 6144 + 4096 + kvg * 128 + s * 8];
    unsigned int o[4];
#pragma unroll
    for (int t = 0; t < 4; ++t) {
      int m = s * 4 + t;  // rope pair index 0..63
      float cs = fc[(key * 64 + m) * 2];
      float sn = fc[(key * 64 + m) * 2 + 1];
      float a = bf2f((unsigned short)v[2 * t]), bb = bf2f((unsigned short)v[2 * t + 1]);
      o[t] = (unsigned int)f2bf(a * cs - bb * sn) | ((unsigned int)f2bf(a * sn + bb * cs) << 16);
    }
    *(uint4*)&Ktil[(size_t)b * 4096 + c * 8] = make_uint4(o[0], o[1], o[2], o[3]);
  }
}

// ---------------- V: transpose + retile ----------------
__global__ void vtile(const unsigned short* __restrict__ QKV, unsigned short* __restrict__ Vtil) {
  int b = blockIdx.x;  // kvg*64 + kvt
  int kvg = b >> 6, kvt = b & 63;
  int tid = threadIdx.x;
#pragma unroll
  for (int cc = 0; cc < 2; ++cc) {
    int c = tid + cc * 256;
    int v = c >> 7, hd = c & 127;
    unsigned short o[8];
#pragma unroll
    for (int t = 0; t < 8; ++t)
      o[t] = QKV[(size_t)(kvt * 32 + v * 8 + t) * 6144 + 5120 + kvg * 128 + hd];
    *(uint4*)&Vtil[(size_t)b * 4096 + c * 8] = *(uint4*)o;
  }
}

// ---------------- QKV GEMM: 256x192 tiles, 256 blocks (full chip) ----------------
// C[2048][6144] = A[2048][4096] * BT[6144][4096]^T. 8 waves 2Mx4N, per-wave 128x48.
// Fragment-major LDS images (conflict-free b128 reads + linear gload_lds staging).
// Stage parts/tile: A0..A3 (kc0,kc0,kc1,kc1 halves), B0..B2. FIFO-traced waits:
// vmcnt(4) end-p1 (ensures t's A2,A3,B2), vmcnt(3) end-p3 (ensures t+1's A0,A1,B0,B1).
__global__ __launch_bounds__(512, 2) void gemm_qkv(const unsigned short* __restrict__ A,
                                                   const unsigned short* __restrict__ BT,
                                                   unsigned short* __restrict__ C) {
  const int K = 4096, N = 6144;
  __shared__ __align__(16) unsigned short smem[2 * 28672];  // 112 KiB
  const int tid = threadIdx.x;
  const int w = tid >> 6, l = tid & 63;
  const int wm = w >> 2, wn = w & 3;
  const int c16 = l & 15, h4 = l >> 4;
  const int wg = ((int)blockIdx.x & 7) * 32 + ((int)blockIdx.x >> 3);  // T1 XCD swizzle
  const int m0 = (wg & 7) << 8, n0 = (wg >> 3) * 192;

  // A image: 2048 chunks, c = kc*1024 + F*64 + lane -> row F*16+(lane&15), col kc*32+(lane>>4)*8
  int growA[4], gcolA[4], growB[3], gcolB[3];
#pragma unroll
  for (int p = 0; p < 4; ++p) {
    int c = p * 512 + tid, ll = c & 63;
    growA[p] = ((c >> 6) & 15) * 16 + (ll & 15);
    gcolA[p] = (c >> 10) * 32 + ((ll >> 4) << 3);
  }
  // B image: 1536 chunks, c = kc*768 + F*64 + lane (F 0..11)
#pragma unroll
  for (int p = 0; p < 3; ++p) {
    int c = p * 512 + tid, ll = c & 63, f6 = c >> 6;
    int kc = (f6 >= 12) ? 1 : 0;
    growB[p] = (f6 - 12 * kc) * 16 + (ll & 15);
    gcolB[p] = kc * 32 + ((ll >> 4) << 3);
  }
  auto stageA = [&](int e, int ks, int p) {
    gload_lds16(A + (size_t)(m0 + growA[p]) * K + ks + gcolA[p],
                &smem[e * 28672 + (p * 512 + tid) * 8]);
  };
  auto stageB = [&](int e, int ks, int p) {
    gload_lds16(BT + (size_t)(n0 + growB[p]) * K + ks + gcolB[p],
                &smem[e * 28672 + 16384 + (p * 512 + tid) * 8]);
  };

  f32x4 acc[2][4][3];
#pragma unroll
  for (int mh = 0; mh < 2; ++mh)
#pragma unroll
    for (int mf = 0; mf < 4; ++mf)
#pragma unroll
      for (int nf = 0; nf < 3; ++nf)
#pragma unroll
        for (int r = 0; r < 4; ++r) acc[mh][mf][nf][r] = 0.f;

  // prologue (tile 0 -> buf 0), issue order A0,A1,B0,B1,A2,A3,B2
  stageA(0, 0, 0); stageA(0, 0, 1); stageB(0, 0, 0); stageB(0, 0, 1);
  stageA(0, 0, 2); stageA(0, 0, 3); stageB(0, 0, 2);
  asm volatile("s_waitcnt vmcnt(3)" ::: "memory");
  __builtin_amdgcn_sched_barrier(0);
  asm volatile("s_barrier" ::: "memory");

  const int nt = K >> 6;
  u16x8 bfr[3];
  for (int t = 0; t < nt; ++t) {
    const int d = t & 1, e = d ^ 1;
    const int dA = d * 28672, dB = dA + 16384;
    const int ks = ((t + 1 < nt) ? t + 1 : t) << 6;  // clamp: redundant, never read
#pragma unroll
    for (int p = 0; p < 4; ++p) {
      const int kc = p >> 1, mh = p & 1;
      u16x8 af[4];
#pragma unroll
      for (int mf = 0; mf < 4; ++mf)
        af[mf] = *(const u16x8*)&smem[dA + ((kc * 16 + wm * 8 + mh * 4 + mf) * 64 + l) * 8];
      if (mh == 0) {
#pragma unroll
        for (int nf = 0; nf < 3; ++nf)
          bfr[nf] = *(const u16x8*)&smem[dB + ((kc * 12 + wn * 3 + nf) * 64 + l) * 8];
      }
      if (p == 0)      { stageA(e, ks, 0); stageA(e, ks, 1); }
      else if (p == 1) { stageB(e, ks, 0); stageB(e, ks, 1); }
      else if (p == 2) { stageA(e, ks, 2); stageA(e, ks, 3); }
      else             { stageB(e, ks, 2); }
      asm volatile("s_barrier" ::: "memory");
      asm volatile("s_waitcnt lgkmcnt(0)" ::: "memory");
      __builtin_amdgcn_sched_barrier(0);
      __builtin_amdgcn_s_setprio(1);
#pragma unroll
      for (int mf = 0; mf < 4; ++mf)
#pragma unroll
        for (int nf = 0; nf < 3; ++nf)
          acc[mh][mf][nf] = mfma16(af[mf], bfr[nf], acc[mh][mf][nf]);
      __builtin_amdgcn_s_setprio(0);
      __builtin_amdgcn_sched_barrier(0);
      if (p == 1) asm volatile("s_waitcnt vmcnt(4)" ::: "memory");
      else if (p == 3) asm volatile("s_waitcnt vmcnt(3)" ::: "memory");
      asm volatile("s_barrier" ::: "memory");
    }
  }
  asm volatile("s_waitcnt vmcnt(0)" ::: "memory");

#pragma unroll
  for (int mh = 0; mh < 2; ++mh)
#pragma unroll
    for (int mf = 0; mf < 4; ++mf)
#pragma unroll
      for (int nf = 0; nf < 3; ++nf)
#pragma unroll
        for (int r = 0; r < 4; ++r) {
          int row = m0 + wm * 128 + mh * 64 + mf * 16 + h4 * 4 + r;
          int col = n0 + wn * 48 + nf * 16 + c16;
          C[(size_t)row * N + col] = f2bf(acc[mh][mf][nf][r]);
        }
}

// ---------------- Out-proj GEMM: 128x256 tiles, 256 blocks, f32 out ----------------
// C[2048][4096] = A[2048][4096] * BT[4096][4096]^T. 8 waves 2Mx4N, per-wave 64x64.
// Phases p = kc*2 + nh. Stage parts: A0(kc0),A1(kc1); B0..B3. Waits: vmcnt(3) at p1,p3.
__global__ __launch_bounds__(512, 2) void gemm_o(const unsigned short* __restrict__ A,
                                                 const unsigned short* __restrict__ BT,
                                                 float* __restrict__ C) {
  const int K = 4096, N = 4096;
  __shared__ __align__(16) unsigned short smem[2 * 24576];  // 96 KiB
  const int tid = threadIdx.x;
  const int w = tid >> 6, l = tid & 63;
  const int wm = w >> 2, wn = w & 3;
  const int c16 = l & 15, h4 = l >> 4;
  const int wg = ((int)blockIdx.x & 7) * 32 + ((int)blockIdx.x >> 3);  // T1 XCD swizzle
  const int m0 = (wg & 15) << 7, n0 = (wg >> 4) << 8;

  // A image: 1024 chunks, c = kc*512 + F*64 + lane (F 0..7)
  int growA[2], gcolA[2], growB[4], gcolB[4];
#pragma unroll
  for (int p = 0; p < 2; ++p) {
    int c = p * 512 + tid, ll = c & 63;
    growA[p] = ((c >> 6) & 7) * 16 + (ll & 15);
    gcolA[p] = (c >> 9) * 32 + ((ll >> 4) << 3);
  }
  // B image: 2048 chunks, c = kc*1024 + F*64 + lane (F 0..15)
#pragma unroll
  for (int p = 0; p < 4; ++p) {
    int c = p * 512 + tid, ll = c & 63;
    growB[p] = ((c >> 6) & 15) * 16 + (ll & 15);
    gcolB[p] = (c >> 10) * 32 + ((ll >> 4) << 3);
  }
  auto stageA = [&](int e, int ks, int p) {
    gload_lds16(A + (size_t)(m0 + growA[p]) * K + ks + gcolA[p],
                &smem[e * 24576 + (p * 512 + tid) * 8]);
  };
  auto stageB = [&](int e, int ks, int p) {
    gload_lds16(BT + (size_t)(n0 + growB[p]) * K + ks + gcolB[p],
                &smem[e * 24576 + 8192 + (p * 512 + tid) * 8]);
  };

  f32x4 acc[4][4];
#pragma unroll
  for (int mf = 0; mf < 4; ++mf)
#pragma unroll
    for (int nc = 0; nc < 4; ++nc)
#pragma unroll
      for (int r = 0; r < 4; ++r) acc[mf][nc][r] = 0.f;

  // prologue (tile 0 -> buf 0), issue order A0,B0,B1,A1,B2,B3
  stageA(0, 0, 0); stageB(0, 0, 0); stageB(0, 0, 1);
  stageA(0, 0, 1); stageB(0, 0, 2); stageB(0, 0, 3);
  asm volatile("s_waitcnt vmcnt(3)" ::: "memory");
  __builtin_amdgcn_sched_barrier(0);
  asm volatile("s_barrier" ::: "memory");

  const int nt = K >> 6;
  u16x8 af[4];
  for (int t = 0; t < nt; ++t) {
    const int d = t & 1, e = d ^ 1;
    const int dA = d * 24576, dB = dA + 8192;
    const int ks = ((t + 1 < nt) ? t + 1 : t) << 6;
#pragma unroll
    for (int p = 0; p < 4; ++p) {
      const int kc = p >> 1, nh = p & 1;
      if (nh == 0) {
#pragma unroll
        for (int mf = 0; mf < 4; ++mf)
          af[mf] = *(const u16x8*)&smem[dA + ((kc * 8 + wm * 4 + mf) * 64 + l) * 8];
      }
      u16x8 bfr[2];
#pragma unroll
      for (int nf = 0; nf < 2; ++nf)
        bfr[nf] = *(const u16x8*)&smem[dB + ((kc * 16 + wn * 4 + nh * 2 + nf) * 64 + l) * 8];
      if (p == 0)      { stageA(e, ks, 0); stageB(e, ks, 0); }
      else if (p == 1) { stageB(e, ks, 1); }
      else if (p == 2) { stageA(e, ks, 1); stageB(e, ks, 2); }
      else             { stageB(e, ks, 3); }
      asm volatile("s_barrier" ::: "memory");
      asm volatile("s_waitcnt lgkmcnt(0)" ::: "memory");
      __builtin_amdgcn_sched_barrier(0);
      __builtin_amdgcn_s_setprio(1);
#pragma unroll
      for (int mf = 0; mf < 4; ++mf)
#pragma unroll
        for (int nf = 0; nf < 2; ++nf)
          acc[mf][nh * 2 + nf] = mfma16(af[mf], bfr[nf], acc[mf][nh * 2 + nf]);
      __builtin_amdgcn_s_setprio(0);
      __builtin_amdgcn_sched_barrier(0);
      if (p == 1 || p == 3) asm volatile("s_waitcnt vmcnt(3)" ::: "memory");
      asm volatile("s_barrier" ::: "memory");
    }
  }
  asm volatile("s_waitcnt vmcnt(0)" ::: "memory");

#pragma unroll
  for (int mf = 0; mf < 4; ++mf)
#pragma unroll
    for (int nc = 0; nc < 4; ++nc)
#pragma unroll
      for (int r = 0; r < 4; ++r) {
        int row = m0 + wm * 64 + mf * 16 + h4 * 4 + r;
        int col = n0 + wn * 64 + nc * 16 + c16;
        C[(size_t)row * N + col] = acc[mf][nc][r];
      }
}

// ---------------- flash attention (causal GQA), 32x32x16 swapped-MFMA ----------------
__global__ __launch_bounds__(256) void attnk(const unsigned short* __restrict__ Q,
                                             const unsigned short* __restrict__ Ktil,
                                             const unsigned short* __restrict__ Vtil,
                                             unsigned short* __restrict__ Ao) {
  __shared__ __align__(16) unsigned short Kbuf[2][4096];  // 8KB per buffer
  __shared__ __align__(16) unsigned short Vbuf[2][4096];
  const int tid = threadIdx.x;
  const int w = tid >> 6, l = tid & 63;
  const int q31 = l & 31, hi = l >> 5;
  const int b = blockIdx.x;
  const int kvg = b & 7;             // kv-group -> XCD affinity
  const int qg = 63 - (b >> 3);      // descending work length for backfill balance
  const int head = kvg * 4 + w;
  const int qrow = qg * 32 + q31;

  u16x8 qf[8];
#pragma unroll
  for (int kc = 0; kc < 8; ++kc)
    qf[kc] = *(const u16x8*)&Q[(size_t)qrow * 6144 + head * 128 + kc * 16 + hi * 8];

  f32x16 accO[4];
#pragma unroll
  for (int f = 0; f < 4; ++f)
#pragma unroll
    for (int r = 0; r < 16; ++r) accO[f][r] = 0.f;
  float m_run = -1e30f, l_run = 0.f;

  const unsigned short* ktb = Ktil + (size_t)kvg * 64 * 4096;
  const unsigned short* vtb = Vtil + (size_t)kvg * 64 * 4096;
  auto STAGE = [&](int d, int t) {
    const unsigned short* ks = ktb + (size_t)t * 4096 + w * 1024 + l * 8;
    const unsigned short* vs = vtb + (size_t)t * 4096 + w * 1024 + l * 8;
    gload_lds16(ks, &Kbuf[d][w * 1024 + l * 8]);
    gload_lds16(ks + 512, &Kbuf[d][w * 1024 + 512 + l * 8]);
    gload_lds16(vs, &Vbuf[d][w * 1024 + l * 8]);
    gload_lds16(vs + 512, &Vbuf[d][w * 1024 + 512 + l * 8]);
  };

  STAGE(0, 0);
  int cur = 0;
  for (int kvt = 0; kvt <= qg; ++kvt) {
    __builtin_amdgcn_s_barrier();
    __builtin_amdgcn_sched_barrier(0);
    if (kvt < qg) {
      STAGE(cur ^ 1, kvt + 1);
      asm volatile("s_waitcnt vmcnt(4)" ::: "memory");
    } else {
      asm volatile("s_waitcnt vmcnt(0)" ::: "memory");
    }
    __builtin_amdgcn_s_barrier();
    __builtin_amdgcn_sched_barrier(0);

    f32x16 s;
#pragma unroll
    for (int r = 0; r < 16; ++r) s[r] = 0.f;
#pragma unroll
    for (int kc = 0; kc < 8; ++kc) {
      u16x8 kf = *(const u16x8*)&Kbuf[cur][((2 * kc + hi) * 32 + q31) * 8];
      s = mfma32(kf, qf[kc], s);
    }

    if (kvt == qg) {
#pragma unroll
      for (int r = 0; r < 16; ++r) {
        int key = (r & 3) + 8 * (r >> 2) + 4 * hi;
        if (key > q31) s[r] = -1e30f;
      }
    }

    float pm = s[0];
#pragma unroll
    for (int r = 1; r < 16; ++r) pm = fmaxf(pm, s[r]);
    pm = fmaxf(pm, __shfl_xor(pm, 32, 64));
    if (!__all(pm - m_run <= 8.f)) {  // T13 defer-max (2^8 bound)
      float mn = fmaxf(m_run, pm);
      float al = exp2_hw(m_run - mn);
      m_run = mn;
      l_run *= al;
#pragma unroll
      for (int f = 0; f < 4; ++f)
#pragma unroll
        for (int r = 0; r < 16; ++r) accO[f][r] *= al;
    }
    float p[16], ls = 0.f;
#pragma unroll
    for (int r = 0; r < 16; ++r) { p[r] = exp2_hw(s[r] - m_run); ls += p[r]; }
    l_run += ls + __shfl_xor(ls, 32, 64);

    unsigned int wv[8], wp[8];
#pragma unroll
    for (int i = 0; i < 8; ++i) wv[i] = cvtpk(p[2 * i], p[2 * i + 1]);
#pragma unroll
    for (int i = 0; i < 8; ++i) wp[i] = (unsigned int)__shfl_xor((int)wv[i], 32, 64);
    union { unsigned int u[4]; u16x8 v; } pf0, pf1;
    pf0.u[0] = hi ? wp[2] : wv[0];
    pf0.u[1] = hi ? wp[3] : wv[1];
    pf0.u[2] = hi ? wv[2] : wp[0];
    pf0.u[3] = hi ? wv[3] : wp[1];
    pf1.u[0] = hi ? wp[6] : wv[4];
    pf1.u[1] = hi ? wp[7] : wv[5];
    pf1.u[2] = hi ? wv[6] : wp[4];
    pf1.u[3] = hi ? wv[7] : wp[5];

#pragma unroll
    for (int f = 0; f < 4; ++f) {
      u16x8 vf0 = *(const u16x8*)&Vbuf[cur][((hi) * 128 + f * 32 + q31) * 8];
      u16x8 vf1 = *(const u16x8*)&Vbuf[cur][((2 + hi) * 128 + f * 32 + q31) * 8];
      accO[f] = mfma32(vf0, pf0.v, accO[f]);
      accO[f] = mfma32(vf1, pf1.v, accO[f]);
    }
    cur ^= 1;
  }

  float linv = 1.0f / l_run;
  unsigned short* orow = Ao + (size_t)qrow * 4096 + head * 128;
#pragma unroll
  for (int f = 0; f < 4; ++f)
#pragma unroll
    for (int g4 = 0; g4 < 4; ++g4) {
      unsigned int lo = (unsigned int)f2bf(accO[f][g4 * 4 + 0] * linv) |
                        ((unsigned int)f2bf(accO[f][g4 * 4 + 1] * linv) << 16);
      unsigned int hi2 = (unsigned int)f2bf(accO[f][g4 * 4 + 2] * linv) |
                         ((unsigned int)f2bf(accO[f][g4 * 4 + 3] * linv) << 16);
      *(uint2*)(orow + f * 32 + 8 * g4 + 4 * hi) = make_uint2(lo, hi2);
    }
}

extern "C" void kernel_launch(void* const* d_in, const int* in_sizes, int n_in,
                              void* d_out, int out_size, void* d_ws, size_t ws_size,
                              hipStream_t stream) {
  (void)in_sizes; (void)n_in; (void)out_size; (void)ws_size;
  const float* x  = (const float*)d_in[0];
  const float* fc = (const float*)d_in[1];
  // d_in[2] = mask: exactly triu(-1e9, k=1) -> causal handled in-kernel
  const float* wq = (const float*)d_in[3];
  const float* wk = (const float*)d_in[4];
  const float* wv = (const float*)d_in[5];
  const float* wo = (const float*)d_in[6];

  const size_t M = 1024 * 1024;
  unsigned short* xb   = (unsigned short*)d_ws;      // 8M shorts; reused as Ab after GEMM1
  unsigned short* wfus = xb   + 8 * M;               // 24M: [wq 4096 | wk 1024 | wv 1024][4096]
  unsigned short* wob  = wfus + 24 * M;              // 16M
  unsigned short* QKV  = wob  + 16 * M;              // 12M: [2048][6144] = Q|K|V
  unsigned short* Ktil = QKV  + 12 * M;              // 2M  tiled+roped K images
  unsigned short* Vtil = Ktil + 2 * M;               // 2M  tiled V^T images
  unsigned short* Ab   = xb;                         // alias: xb dead after GEMM1

  cvtk<<<dim3(8 * M / 1024), 256, 0, stream>>>(x, xb, 8 * M);
  cvtk<<<dim3(16 * M / 1024), 256, 0, stream>>>(wq, wfus, 16 * M);
  cvtk<<<dim3(4 * M / 1024), 256, 0, stream>>>(wk, wfus + 16 * M, 4 * M);
  cvtk<<<dim3(4 * M / 1024), 256, 0, stream>>>(wv, wfus + 20 * M, 4 * M);
  cvtk<<<dim3(16 * M / 1024), 256, 0, stream>>>(wo, wob, 16 * M);

  // fused QKV projection: [2048][6144] = xb @ wfus^T   (256 blocks, full chip)
  gemm_qkv<<<dim3(256), 512, 0, stream>>>(xb, wfus, QKV);

  ropek<<<dim3(2048 * 32 * 64 / 256), 256, 0, stream>>>(QKV, fc, 5, 6144, SCALE_F * LOG2E_F);
  ktile<<<dim3(512), 256, 0, stream>>>(QKV, fc, Ktil);
  vtile<<<dim3(512), 256, 0, stream>>>(QKV, Vtil);

  attnk<<<dim3(512), 256, 0, stream>>>(QKV, Ktil, Vtil, Ab);

  // output projection (256 blocks, full chip)
  gemm_o<<<dim3(256), 512, 0, stream>>>(Ab, wob, (float*)d_out);
}